// Round 10
// baseline (173.710 us; speedup 1.0000x reference)
//
#include <hip/hip_runtime.h>

// deformMP: B=4, Cc=256, ci=64, H=W=128, GN groups=32, eps=1e-5
// ws (floats, no aliases, ~56 MB):
//   xdT[4.19M] offs[1.18M] t3bf[8.39M fl-equiv] mrs1[256] mrs2[256]
//   wA1f[8.2K] wBf[18.4K] wofBf[9.2K] w3Bf[16.4K] ps[65.5K] ps2[131K]

#define HW 16384
#define WIDTH 128

typedef __attribute__((ext_vector_type(8))) short bf16x8;
typedef __attribute__((ext_vector_type(4))) float f32x4;

__device__ __forceinline__ unsigned short f2bf(float f) {
  unsigned int u = __float_as_uint(f);
  u = (u + 0x7fffu + ((u >> 16) & 1u)) >> 16;  // RNE
  return (unsigned short)u;
}

// ---- K0: weight repack ----
__global__ __launch_bounds__(256) void k_prep(const float* __restrict__ w1, const float* __restrict__ w3,
                                              const float* __restrict__ wdef, const float* __restrict__ woff,
                                              unsigned short* __restrict__ wA1f,
                                              unsigned short* __restrict__ wBf,
                                              unsigned short* __restrict__ wofBf,
                                              unsigned short* __restrict__ w3Bf) {
  int i = blockIdx.x * 256 + threadIdx.x;
  if (i < 16384) {
    // conv1 A-frags (M=o side): [kt=8][m=4][lane=64][j=8]; elem = w1[o=m*16+(lane&15)][c=kt*32+(lane>>4)*8+j]
    int j = i & 7;
    int lane = (i >> 3) & 63;
    int m = (i >> 9) & 3;
    int kt = i >> 11;
    int o = (m << 4) + (lane & 15);
    int c = kt * 32 + ((lane >> 4) << 3) + j;
    wA1f[i] = f2bf(w1[(size_t)o * 256 + c]);
  }
  if (i < 36864) {
    // deform B-frags: [kt=18][n=4][lane=64][j=8]; elem = Wd[K=kt*32+(lane>>4)*8+j][o=n*16+(lane&15)]
    int j = i & 7;
    int lane = (i >> 3) & 63;
    int n = (i >> 9) & 3;
    int kt = i >> 11;
    int kk = kt * 32 + ((lane >> 4) << 3) + j;
    int tap = kk >> 6, c = kk & 63;
    int o = (n << 4) + (lane & 15);
    wBf[i] = f2bf(wdef[(size_t)o * 576 + c * 9 + tap]);
  }
  if (i < 18432) {
    // offs-conv B-frags: [kt=18][n=2][lane=64][j=8]; zero-pad o>=18
    int j = i & 7;
    int lane = (i >> 3) & 63;
    int n = (i >> 9) & 1;
    int kt = i >> 10;
    int kk = kt * 32 + ((lane >> 4) << 3) + j;
    int tap = kk >> 6, c = kk & 63;
    int o = (n << 4) + (lane & 15);
    wofBf[i] = (o < 18) ? f2bf(woff[((size_t)(o * 64 + c)) * 9 + tap]) : (unsigned short)0;
  }
  if (i < 32768) {
    // conv2 B-frags: [kt=2][n=16][lane=64][j=8]; elem = W3[c=kt*32+(lane>>4)*8+j][o=n*16+(lane&15)]
    int j = i & 7;
    int lane = (i >> 3) & 63;
    int n = (i >> 9) & 15;
    int kt = i >> 13;
    int c = kt * 32 + ((lane >> 4) << 3) + j;
    int o = (n << 4) + (lane & 15);
    w3Bf[i] = f2bf(w3[(size_t)o * 64 + c]);
  }
}

// ---- K1: conv1x1 256->64 via bf16 MFMA, writes NHWC directly + GN1 partials.
// Block = 256 thr (4 waves); wave = 16-px tile; M=64 outs (4 m-tiles), K=256 (8 kt).
// D: col(lane&15)=px, row((lane>>4)*4+r)=o within m-tile -> float4 NHWC stores.
__global__ __launch_bounds__(256) void k_conv1m(const float* __restrict__ x,
                                                const unsigned short* __restrict__ wA1f,
                                                float* __restrict__ xdT, float* __restrict__ ps) {
  __shared__ float lds_s[4][32], lds_ss[4][32];
  int tid = threadIdx.x;
  int wave = tid >> 6, lane = tid & 63;
  int b = blockIdx.x >> 8;
  int chunk = blockIdx.x & 255;
  int px0 = (chunk << 6) + (wave << 4);
  int pxl = lane & 15, q = lane >> 4;
  const float* xb = x + (size_t)b * 256 * HW + px0 + pxl;
  const bf16x8* wAp = (const bf16x8*)wA1f;
  f32x4 acc[4];
#pragma unroll
  for (int m = 0; m < 4; m++) acc[m] = (f32x4){0.f, 0.f, 0.f, 0.f};
#pragma unroll
  for (int kt = 0; kt < 8; kt++) {
    int cb = kt * 32 + (q << 3);
    float v[8];
#pragma unroll
    for (int j = 0; j < 8; j++) v[j] = xb[(size_t)(cb + j) * HW];
    unsigned int u[4];
    asm("v_cvt_pk_bf16_f32 %0, %1, %2" : "=v"(u[0]) : "v"(v[0]), "v"(v[1]));
    asm("v_cvt_pk_bf16_f32 %0, %1, %2" : "=v"(u[1]) : "v"(v[2]), "v"(v[3]));
    asm("v_cvt_pk_bf16_f32 %0, %1, %2" : "=v"(u[2]) : "v"(v[4]), "v"(v[5]));
    asm("v_cvt_pk_bf16_f32 %0, %1, %2" : "=v"(u[3]) : "v"(v[6]), "v"(v[7]));
    bf16x8 bfrag;
    ((unsigned int*)&bfrag)[0] = u[0];
    ((unsigned int*)&bfrag)[1] = u[1];
    ((unsigned int*)&bfrag)[2] = u[2];
    ((unsigned int*)&bfrag)[3] = u[3];
#pragma unroll
    for (int m = 0; m < 4; m++) {
      bf16x8 af = wAp[(kt * 4 + m) * 64 + lane];
      acc[m] = __builtin_amdgcn_mfma_f32_16x16x32_bf16(af, bfrag, acc[m], 0, 0, 0);
    }
  }
  // NHWC stores: xdT[px][o], o = m*16 + q*4 + r
  float* xo = xdT + ((size_t)b * HW + px0 + pxl) * 64 + (q << 2);
#pragma unroll
  for (int m = 0; m < 4; m++)
    *(float4*)(xo + m * 16) = make_float4(acc[m][0], acc[m][1], acc[m][2], acc[m][3]);
  // GN1 partials: g = o>>1 = m*8 + q*2 + h (h = r>>1); reduce over 16 px lanes
  float s[8], sq[8];
#pragma unroll
  for (int m = 0; m < 4; m++)
#pragma unroll
    for (int h = 0; h < 2; h++) {
      float a = acc[m][2 * h] + acc[m][2 * h + 1];
      float qq = acc[m][2 * h] * acc[m][2 * h] + acc[m][2 * h + 1] * acc[m][2 * h + 1];
      s[m * 2 + h] = a; sq[m * 2 + h] = qq;
    }
#pragma unroll
  for (int i = 0; i < 8; i++) {
#pragma unroll
    for (int off = 8; off; off >>= 1) {
      s[i] += __shfl_down(s[i], off, 16);
      sq[i] += __shfl_down(sq[i], off, 16);
    }
  }
  if (pxl == 0) {
#pragma unroll
    for (int i = 0; i < 8; i++) {
      int m = i >> 1, h = i & 1;
      int g = m * 8 + q * 2 + h;
      lds_s[wave][g] = s[i];
      lds_ss[wave][g] = sq[i];
    }
  }
  __syncthreads();
  if (tid < 32) {
    float S = lds_s[0][tid] + lds_s[1][tid] + lds_s[2][tid] + lds_s[3][tid];
    float SS = lds_ss[0][tid] + lds_ss[1][tid] + lds_ss[2][tid] + lds_ss[3][tid];
    int bg = b * 32 + tid;
    ps[(bg * 256 + chunk) * 2] = S;
    ps[(bg * 256 + chunk) * 2 + 1] = SS;
  }
}

// ---- K2: finalize GN stats (S chunks per bg) ----
__global__ __launch_bounds__(128) void k_gnfin(const float* __restrict__ ps, float* __restrict__ mrs,
                                               int S, float n) {
  int bg = threadIdx.x;
  float s = 0.f, ss = 0.f;
  for (int sl = 0; sl < S; sl++) { s += ps[(bg * S + sl) * 2]; ss += ps[(bg * S + sl) * 2 + 1]; }
  float mu = s / n;
  float var = ss / n - mu * mu;
  mrs[bg] = mu;
  mrs[128 + bg] = rsqrtf(var + 1e-5f);
}

// ---- K3: GN1 + ReLU in place on xdT (NHWC, elementwise) ----
__global__ __launch_bounds__(256) void k_gnapply(float* __restrict__ xdT, const float* __restrict__ mrs,
                                                 const float* __restrict__ g1, const float* __restrict__ b1) {
  int i4 = blockIdx.x * 256 + threadIdx.x;  // 1,048,576 float4
  int b = i4 >> 18;                          // HW*64/4 = 2^18 per batch
  int c4 = i4 & 15;                          // 16 float4 per px; c = c4*4..c4*4+3
  int g0 = c4 * 2, g1i = c4 * 2 + 1;
  float mu0 = mrs[b * 32 + g0], rs0 = mrs[128 + b * 32 + g0];
  float mu1 = mrs[b * 32 + g1i], rs1 = mrs[128 + b * 32 + g1i];
  float4 gv = *(const float4*)(g1 + c4 * 4);
  float4 bv = *(const float4*)(b1 + c4 * 4);
  float ga0 = gv.x * rs0, be0 = bv.x - mu0 * ga0;
  float ga1 = gv.y * rs0, be1 = bv.y - mu0 * ga1;
  float ga2 = gv.z * rs1, be2 = bv.z - mu1 * ga2;
  float ga3 = gv.w * rs1, be3 = bv.w - mu1 * ga3;
  float4 v = ((const float4*)xdT)[i4];
  v.x = fmaxf(v.x * ga0 + be0, 0.f);
  v.y = fmaxf(v.y * ga1 + be1, 0.f);
  v.z = fmaxf(v.z * ga2 + be2, 0.f);
  v.w = fmaxf(v.w * ga3 + be3, 0.f);
  ((float4*)xdT)[i4] = v;
}

// ---- K4: offsets conv3x3 64->18 via bf16 MFMA (fixed-tap im2col GEMM) ----
__global__ __launch_bounds__(576, 2) void k_off_mfma(const float* __restrict__ xdT,
                                                     const unsigned short* __restrict__ wofBf,
                                                     float* __restrict__ offs) {
  __shared__ unsigned short A[72 * 65 * 8];  // 74,880 B
  int tid = threadIdx.x;
  int bb = blockIdx.x >> 8;
  int px0 = (blockIdx.x & 255) << 6;
  const char* xbt = (const char*)(xdT + (size_t)bb * 64 * HW);
  int wave = tid >> 6;  // tap 0..8
  int lane = tid & 63;
  {
    int q = lane >> 4;
    int ch = lane & 15;
    int co = ch << 4;
    int kcb = wave * 8 + (ch >> 1);
    int wbase = kcb * (65 * 16) + ((ch & 1) << 3);
    int ky = wave / 3 - 1, kx = wave % 3 - 1;
#pragma unroll 2
    for (int g = 0; g < 16; ++g) {
      int src = 4 * g + q;
      int px = px0 + src;
      int sy = (px >> 7) + ky;
      int sx = (px & 127) + kx;
      bool valid = ((unsigned)sy < 128u) && ((unsigned)sx < 128u);
      float4 v = make_float4(0.f, 0.f, 0.f, 0.f);
      if (valid) v = *(const float4*)(xbt + (((sy << 7) + sx) << 8) + co);
      unsigned int r0, r1;
      asm("v_cvt_pk_bf16_f32 %0, %1, %2" : "=v"(r0) : "v"(v.x), "v"(v.y));
      asm("v_cvt_pk_bf16_f32 %0, %1, %2" : "=v"(r1) : "v"(v.z), "v"(v.w));
      *(uint2*)((char*)A + wbase + src * 16) = make_uint2(r0, r1);
    }
  }
  __syncthreads();
  if (wave >= 8) return;
  int n = wave & 1;
  int mh = wave >> 1;
  int r0r = mh * 16 + (lane & 15);
  int kq = lane >> 4;
  const bf16x8* wp = (const bf16x8*)wofBf;
  f32x4 acc = {0.f, 0.f, 0.f, 0.f};
#pragma unroll 3
  for (int kt = 0; kt < 18; kt++) {
    bf16x8 bk = wp[(kt * 2 + n) * 64 + lane];
    int kc = kt * 4 + kq;
    bf16x8 a0 = *(const bf16x8*)((const char*)A + (kc * 65 + r0r) * 16);
    acc = __builtin_amdgcn_mfma_f32_16x16x32_bf16(a0, bk, acc, 0, 0, 0);
  }
  int o = n * 16 + (lane & 15);
  if (o < 18) {
    int prow = mh * 16 + ((lane >> 4) << 2);
    float* op = offs + (size_t)bb * 18 * HW + (size_t)o * HW + px0 + prow;
#pragma unroll
    for (int r = 0; r < 4; r++) op[r] = acc[r];
  }
}

// ---- K5: fused deform conv + residual + conv1x1 64->256 + GN2 partials, all MFMA ----
__global__ __launch_bounds__(576, 5) void k_dcf(const float* __restrict__ xdT,
                                                const float* __restrict__ offs,
                                                const unsigned short* __restrict__ wBf,
                                                const unsigned short* __restrict__ w3Bf,
                                                unsigned short* __restrict__ t3,
                                                float* __restrict__ ps2) {
  __shared__ unsigned short A[72 * 65 * 8];  // 74,880 B
  int tid = threadIdx.x;
  int bb = blockIdx.x >> 8;
  int tileid = blockIdx.x & 255;
  int px0 = tileid << 6;
  const float* xtf = xdT + (size_t)bb * 64 * HW;
  const char* xbt = (const char*)xtf;
  int wave = tid >> 6;
  int lane = tid & 63;

  float w00, w01, w10, w11;
  int a00, a01, a10, a11;
  {
    int px = px0 + lane;
    int y = px >> 7, xc = px & 127;
    const float* ob = offs + (size_t)bb * 18 * HW + px;
    float dy = ob[(size_t)(2 * wave) * HW];
    float dx = ob[(size_t)(2 * wave + 1) * HW];
    float py = (float)(y + wave / 3 - 1) + dy;
    float pxx = (float)(xc + wave % 3 - 1) + dx;
    float y0f = floorf(py), x0f = floorf(pxx);
    float ay = py - y0f, ax = pxx - x0f;
    int y0 = (int)y0f, x0 = (int)x0f;
    int y1i = y0 + 1, x1i = x0 + 1;
    float by0 = 1.f - ay, bx0 = 1.f - ax;
    bool vy0 = (unsigned)y0 < 128u, vy1 = (unsigned)y1i < 128u;
    bool vx0 = (unsigned)x0 < 128u, vx1 = (unsigned)x1i < 128u;
    w00 = (vy0 && vx0) ? by0 * bx0 : 0.f;
    w01 = (vy0 && vx1) ? by0 * ax : 0.f;
    w10 = (vy1 && vx0) ? ay * bx0 : 0.f;
    w11 = (vy1 && vx1) ? ay * ax : 0.f;
    int iy0 = min(max(y0, 0), 127), iy1 = min(max(y1i, 0), 127);
    int ix0 = min(max(x0, 0), 127), ix1 = min(max(x1i, 0), 127);
    a00 = (iy0 * WIDTH + ix0) << 8;
    a01 = (iy0 * WIDTH + ix1) << 8;
    a10 = (iy1 * WIDTH + ix0) << 8;
    a11 = (iy1 * WIDTH + ix1) << 8;
  }

  // Phase A: gather
  {
    int q = lane >> 4;
    int ch = lane & 15;
    int co = ch << 4;
    int kcb = wave * 8 + (ch >> 1);
    int wbase = kcb * (65 * 16) + ((ch & 1) << 3);
#pragma unroll 2
    for (int g = 0; g < 16; ++g) {
      int src = 4 * g + q;
      float j0 = __shfl(w00, src), j1 = __shfl(w01, src);
      float j2 = __shfl(w10, src), j3 = __shfl(w11, src);
      int b0 = __shfl(a00, src), b1 = __shfl(a01, src);
      int b2 = __shfl(a10, src), b3 = __shfl(a11, src);
      float4 v0 = *(const float4*)(xbt + b0 + co);
      float4 v1 = *(const float4*)(xbt + b1 + co);
      float4 v2 = *(const float4*)(xbt + b2 + co);
      float4 v3 = *(const float4*)(xbt + b3 + co);
      float sx = j0 * v0.x + j1 * v1.x + j2 * v2.x + j3 * v3.x;
      float sy = j0 * v0.y + j1 * v1.y + j2 * v2.y + j3 * v3.y;
      float sz = j0 * v0.z + j1 * v1.z + j2 * v2.z + j3 * v3.z;
      float sw = j0 * v0.w + j1 * v1.w + j2 * v2.w + j3 * v3.w;
      unsigned int r0, r1;
      asm("v_cvt_pk_bf16_f32 %0, %1, %2" : "=v"(r0) : "v"(sx), "v"(sy));
      asm("v_cvt_pk_bf16_f32 %0, %1, %2" : "=v"(r1) : "v"(sz), "v"(sw));
      *(uint2*)((char*)A + wbase + src * 16) = make_uint2(r0, r1);
    }
  }
  __syncthreads();

  // Phase B: GEMM1 + residual (waves 0..7)
  int n1 = wave & 3;
  int mh = wave >> 2;
  f32x4 acc0 = {0.f, 0.f, 0.f, 0.f};
  f32x4 acc1 = {0.f, 0.f, 0.f, 0.f};
  if (wave < 8) {
    int r0r = mh * 32 + (lane & 15);
    int kq = lane >> 4;
    const bf16x8* wp = (const bf16x8*)wBf;
#pragma unroll 3
    for (int kt = 0; kt < 18; kt++) {
      bf16x8 bk = wp[(kt * 4 + n1) * 64 + lane];
      int kc = kt * 4 + kq;
      bf16x8 a0 = *(const bf16x8*)((const char*)A + (kc * 65 + r0r) * 16);
      bf16x8 a1 = *(const bf16x8*)((const char*)A + (kc * 65 + r0r + 16) * 16);
      acc0 = __builtin_amdgcn_mfma_f32_16x16x32_bf16(a0, bk, acc0, 0, 0, 0);
      acc1 = __builtin_amdgcn_mfma_f32_16x16x32_bf16(a1, bk, acc1, 0, 0, 0);
    }
    int c = n1 * 16 + (lane & 15);
    int pb = px0 + mh * 32 + ((lane >> 4) << 2);
#pragma unroll
    for (int r = 0; r < 4; r++) {
      acc0[r] += xtf[(size_t)(pb + r) * 64 + c];
      acc1[r] += xtf[(size_t)(pb + 16 + r) * 64 + c];
    }
  }
  __syncthreads();

  // Phase C: write A2 (bf16 chunk-major [kc=8][row pad65][16B]) into A's head
  if (wave < 8) {
    int c = n1 * 16 + (lane & 15);
    char* base = (char*)A + (c >> 3) * 1040 + (c & 7) * 2;
    int pxr = mh * 32 + ((lane >> 4) << 2);
#pragma unroll
    for (int r = 0; r < 4; r++) {
      *(unsigned short*)(base + (size_t)(pxr + r) * 16) = f2bf(acc0[r]);
      *(unsigned short*)(base + (size_t)(pxr + 16 + r) * 16) = f2bf(acc1[r]);
    }
  }
  __syncthreads();
  if (wave >= 8) return;

  // Phase D: GEMM2 (M=64, N=256, K=64)
  f32x4 cA[4], cB[4];
#pragma unroll
  for (int ni = 0; ni < 4; ni++) {
    cA[ni] = (f32x4){0.f, 0.f, 0.f, 0.f};
    cB[ni] = (f32x4){0.f, 0.f, 0.f, 0.f};
  }
  {
    int kq = lane >> 4;
    int mt0 = (wave >> 2) * 2;
    const bf16x8* wp2 = (const bf16x8*)w3Bf;
#pragma unroll
    for (int kt = 0; kt < 2; kt++) {
      int kc = kt * 4 + kq;
      bf16x8 aA = *(const bf16x8*)((const char*)A + (size_t)(kc * 65 + mt0 * 16 + (lane & 15)) * 16);
      bf16x8 aB = *(const bf16x8*)((const char*)A + (size_t)(kc * 65 + (mt0 + 1) * 16 + (lane & 15)) * 16);
#pragma unroll
      for (int ni = 0; ni < 4; ni++) {
        int ng = n1 * 4 + ni;
        bf16x8 bk = wp2[(kt * 16 + ng) * 64 + lane];
        cA[ni] = __builtin_amdgcn_mfma_f32_16x16x32_bf16(aA, bk, cA[ni], 0, 0, 0);
        cB[ni] = __builtin_amdgcn_mfma_f32_16x16x32_bf16(aB, bk, cB[ni], 0, 0, 0);
      }
    }
  }
#pragma unroll
  for (int ni = 0; ni < 4; ni++) {
    float s = 0.f, q = 0.f;
#pragma unroll
    for (int r = 0; r < 4; r++) {
      float v0 = cA[ni][r], v1 = cB[ni][r];
      s += v0 + v1; q += v0 * v0 + v1 * v1;
    }
    s += __shfl_down(s, 32); q += __shfl_down(q, 32);
    s += __shfl_down(s, 16); q += __shfl_down(q, 16);
    s += __shfl_down(s, 4);  q += __shfl_down(q, 4);
    s += __shfl_down(s, 2);  q += __shfl_down(q, 2);
    s += __shfl_down(s, 1);  q += __shfl_down(q, 1);
    if (lane == 0 || lane == 8) {
      int g = (n1 * 4 + ni) * 2 + (lane >> 3);
      int slot = ((bb * 32 + g) * 256 + tileid) * 2 + (wave >> 2);
      ps2[slot * 2] = s;
      ps2[slot * 2 + 1] = q;
    }
  }
  unsigned short* tb = t3 + (size_t)bb * 256 * HW + px0;
  int mtq = (wave >> 2) * 32 + ((lane >> 4) << 2);
#pragma unroll
  for (int ni = 0; ni < 4; ni++) {
    int o = (n1 * 4 + ni) * 16 + (lane & 15);
    unsigned short* p0 = tb + (size_t)o * HW + mtq;
    unsigned int u0, u1, u2, u3;
    asm("v_cvt_pk_bf16_f32 %0, %1, %2" : "=v"(u0) : "v"(cA[ni][0]), "v"(cA[ni][1]));
    asm("v_cvt_pk_bf16_f32 %0, %1, %2" : "=v"(u1) : "v"(cA[ni][2]), "v"(cA[ni][3]));
    asm("v_cvt_pk_bf16_f32 %0, %1, %2" : "=v"(u2) : "v"(cB[ni][0]), "v"(cB[ni][1]));
    asm("v_cvt_pk_bf16_f32 %0, %1, %2" : "=v"(u3) : "v"(cB[ni][2]), "v"(cB[ni][3]));
    *(uint2*)p0 = make_uint2(u0, u1);
    *(uint2*)(p0 + 16) = make_uint2(u2, u3);
  }
}

// ---- K7: finalize GN2 stats (512 slots per bg) ----
__global__ __launch_bounds__(128) void k_gnfin2(const float* __restrict__ ps2, float* __restrict__ mrs) {
  int bg = threadIdx.x;
  float s = 0.f, ss = 0.f;
  for (int i = 0; i < 512; i++) { s += ps2[(bg * 512 + i) * 2]; ss += ps2[(bg * 512 + i) * 2 + 1]; }
  const float n = 131072.f;
  float mu = s / n;
  float var = ss / n - mu * mu;
  mrs[bg] = mu;
  mrs[128 + bg] = rsqrtf(var + 1e-5f);
}

// ---- K8: out = relu(gn2(t3_bf16)) + x ----
__global__ __launch_bounds__(256) void k_final(const unsigned short* __restrict__ t3, const float* __restrict__ x,
                                               const float* __restrict__ mrs, const float* __restrict__ g3,
                                               const float* __restrict__ b3, float* __restrict__ out) {
  int i4 = blockIdx.x * 256 + threadIdx.x;
  int b = i4 >> 20;
  int c = (i4 >> 12) & 255;
  int g = c >> 3;
  float mu = mrs[b * 32 + g], rs = mrs[128 + b * 32 + g];
  float ga = g3[c] * rs, be = b3[c] - mu * ga;
  uint2 tv = ((const uint2*)t3)[i4];
  float t0 = __uint_as_float(tv.x << 16);
  float t1 = __uint_as_float(tv.x & 0xffff0000u);
  float t2 = __uint_as_float(tv.y << 16);
  float t3v = __uint_as_float(tv.y & 0xffff0000u);
  float4 xv = ((const float4*)x)[i4];
  float4 r;
  r.x = fmaxf(t0 * ga + be, 0.f) + xv.x;
  r.y = fmaxf(t1 * ga + be, 0.f) + xv.y;
  r.z = fmaxf(t2 * ga + be, 0.f) + xv.z;
  r.w = fmaxf(t3v * ga + be, 0.f) + xv.w;
  ((float4*)out)[i4] = r;
}

extern "C" void kernel_launch(void* const* d_in, const int* in_sizes, int n_in,
                              void* d_out, int out_size, void* d_ws, size_t ws_size,
                              hipStream_t stream) {
  const float* x    = (const float*)d_in[0];
  const float* w1   = (const float*)d_in[1];
  const float* g1   = (const float*)d_in[2];
  const float* b1   = (const float*)d_in[3];
  const float* woff = (const float*)d_in[4];
  const float* wdef = (const float*)d_in[5];
  const float* w3   = (const float*)d_in[6];
  const float* g3   = (const float*)d_in[7];
  const float* b3   = (const float*)d_in[8];
  float* ws = (float*)d_ws;

  float* xdT  = ws;                       // 4,194,304 (NHWC; raw then normalized in place)
  float* offs = xdT + 4194304;            // 1,179,648
  unsigned short* t3 = (unsigned short*)(offs + 1179648);  // 16,777,216 ush = 8,388,608 fl
  float* base = offs + 1179648 + 8388608;
  float* mrs1 = base;                     // 256
  float* mrs2 = mrs1 + 256;               // 256
  unsigned short* wA1f  = (unsigned short*)(mrs2 + 256);          // 16,384 ush = 8,192 fl
  unsigned short* wBf   = (unsigned short*)(mrs2 + 256 + 8192);   // 36,864 ush = 18,432 fl
  unsigned short* wofBf = (unsigned short*)(mrs2 + 256 + 8192 + 18432);  // 18,432 ush = 9,216 fl
  unsigned short* w3Bf  = (unsigned short*)(mrs2 + 256 + 8192 + 18432 + 9216);  // 32,768 ush = 16,384 fl
  float* ps   = mrs2 + 256 + 8192 + 18432 + 9216 + 16384;  // 65,536
  float* ps2  = ps + 65536;               // 131,072
  float* out  = (float*)d_out;

  hipLaunchKernelGGL(k_prep, dim3(144), dim3(256), 0, stream, w1, w3, wdef, woff, wA1f, wBf, wofBf, w3Bf);
  hipLaunchKernelGGL(k_conv1m, dim3(1024), dim3(256), 0, stream, x, wA1f, xdT, ps);
  hipLaunchKernelGGL(k_gnfin, dim3(1), dim3(128), 0, stream, ps, mrs1, 256, (float)(2 * HW));
  hipLaunchKernelGGL(k_gnapply, dim3(4096), dim3(256), 0, stream, xdT, mrs1, g1, b1);
  hipLaunchKernelGGL(k_off_mfma, dim3(1024), dim3(576), 0, stream, xdT, wofBf, offs);
  hipLaunchKernelGGL(k_dcf, dim3(1024), dim3(576), 0, stream, xdT, offs, wBf, w3Bf, t3, ps2);
  hipLaunchKernelGGL(k_gnfin2, dim3(1), dim3(128), 0, stream, ps2, mrs2);
  hipLaunchKernelGGL(k_final, dim3(16384), dim3(256), 0, stream, t3, x, mrs2, g3, b3, out);
}

// Round 11
// 136.494 us; speedup vs baseline: 1.2727x; 1.2727x over previous
//
#include <hip/hip_runtime.h>

// deformMP: B=4, Cc=256, ci=64, H=W=128, GN groups=32, eps=1e-5
// ws (floats, no aliases, ~56.6 MB):
//   xdT[4.19M] offs[1.18M] t3bf[8.39M fl-equiv] mrs1[256] mrs2[256]
//   wA1f[8.2K] wBf[18.4K] wofBf[9.2K] w3Bf[16.4K] ps[65.5K] ps2[262.1K]

#define HW 16384
#define WIDTH 128

typedef __attribute__((ext_vector_type(8))) short bf16x8;
typedef __attribute__((ext_vector_type(4))) float f32x4;

__device__ __forceinline__ unsigned short f2bf(float f) {
  unsigned int u = __float_as_uint(f);
  u = (u + 0x7fffu + ((u >> 16) & 1u)) >> 16;  // RNE
  return (unsigned short)u;
}

// ---- K0: weight repack (unchanged) ----
__global__ __launch_bounds__(256) void k_prep(const float* __restrict__ w1, const float* __restrict__ w3,
                                              const float* __restrict__ wdef, const float* __restrict__ woff,
                                              unsigned short* __restrict__ wA1f,
                                              unsigned short* __restrict__ wBf,
                                              unsigned short* __restrict__ wofBf,
                                              unsigned short* __restrict__ w3Bf) {
  int i = blockIdx.x * 256 + threadIdx.x;
  if (i < 16384) {
    // conv1 A-frags: [kt=8][m=4][lane=64][j=8]; elem = w1[o=m*16+(lane&15)][c=kt*32+(lane>>4)*8+j]
    int j = i & 7;
    int lane = (i >> 3) & 63;
    int m = (i >> 9) & 3;
    int kt = i >> 11;
    int o = (m << 4) + (lane & 15);
    int c = kt * 32 + ((lane >> 4) << 3) + j;
    wA1f[i] = f2bf(w1[(size_t)o * 256 + c]);
  }
  if (i < 36864) {
    // deform B-frags: [kt=18][n=4][lane=64][j=8]
    int j = i & 7;
    int lane = (i >> 3) & 63;
    int n = (i >> 9) & 3;
    int kt = i >> 11;
    int kk = kt * 32 + ((lane >> 4) << 3) + j;
    int tap = kk >> 6, c = kk & 63;
    int o = (n << 4) + (lane & 15);
    wBf[i] = f2bf(wdef[(size_t)o * 576 + c * 9 + tap]);
  }
  if (i < 18432) {
    // offs-conv B-frags: [kt=18][n=2][lane=64][j=8]; zero-pad o>=18
    int j = i & 7;
    int lane = (i >> 3) & 63;
    int n = (i >> 9) & 1;
    int kt = i >> 10;
    int kk = kt * 32 + ((lane >> 4) << 3) + j;
    int tap = kk >> 6, c = kk & 63;
    int o = (n << 4) + (lane & 15);
    wofBf[i] = (o < 18) ? f2bf(woff[((size_t)(o * 64 + c)) * 9 + tap]) : (unsigned short)0;
  }
  if (i < 32768) {
    // conv2 B-frags: [kt=2][n=16][lane=64][j=8]
    int j = i & 7;
    int lane = (i >> 3) & 63;
    int n = (i >> 9) & 15;
    int kt = i >> 13;
    int c = kt * 32 + ((lane >> 4) << 3) + j;
    int o = (n << 4) + (lane & 15);
    w3Bf[i] = f2bf(w3[(size_t)o * 64 + c]);
  }
}

// ---- K1: conv1x1 256->64 via bf16 MFMA with LDS-staged x, NHWC write + GN1 partials.
// Block = 256 thr (4 waves), tile = 64 px; wave -> 16-px n-tile; K=256 in 4 c-blocks of 64.
// Stage: coalesced float4 loads -> bf16 transpose xs[px][c] (pitch 72) -> b128 B-frags.
__global__ __launch_bounds__(256) void k_conv1m(const float* __restrict__ x,
                                                const unsigned short* __restrict__ wA1f,
                                                float* __restrict__ xdT, float* __restrict__ ps) {
  __shared__ unsigned short xs[64][72];  // 9,216 B (144B pitch: 16B-aligned, 4-bank px step)
  __shared__ float lds_s[4][32], lds_ss[4][32];
  int tid = threadIdx.x;
  int wave = tid >> 6, lane = tid & 63;
  int b = blockIdx.x >> 8;
  int chunk = blockIdx.x & 255;
  int px0 = chunk << 6;
  int pxl = lane & 15, q = lane >> 4;
  const float* xb = x + (size_t)b * 256 * HW + px0;
  const bf16x8* wAp = (const bf16x8*)wA1f;
  f32x4 acc[4];
#pragma unroll
  for (int m = 0; m < 4; m++) acc[m] = (f32x4){0.f, 0.f, 0.f, 0.f};

  for (int cb = 0; cb < 4; cb++) {
    __syncthreads();  // protect previous iteration's reads
    // stage 64c x 64px: idx = r*256+tid -> c = idx>>4, quad = idx&15
#pragma unroll
    for (int r = 0; r < 4; r++) {
      int idx = r * 256 + tid;
      int c = idx >> 4;
      int qd = idx & 15;
      float4 v = *(const float4*)(xb + (size_t)(cb * 64 + c) * HW + qd * 4);
      xs[qd * 4 + 0][c] = f2bf(v.x);
      xs[qd * 4 + 1][c] = f2bf(v.y);
      xs[qd * 4 + 2][c] = f2bf(v.z);
      xs[qd * 4 + 3][c] = f2bf(v.w);
    }
    __syncthreads();
#pragma unroll
    for (int kt = 0; kt < 2; kt++) {
      bf16x8 bfrag = *(const bf16x8*)&xs[wave * 16 + pxl][kt * 32 + q * 8];
      int ktG = cb * 2 + kt;
#pragma unroll
      for (int m = 0; m < 4; m++) {
        bf16x8 af = wAp[(ktG * 4 + m) * 64 + lane];
        acc[m] = __builtin_amdgcn_mfma_f32_16x16x32_bf16(af, bfrag, acc[m], 0, 0, 0);
      }
    }
  }
  // NHWC stores: xdT[px][o], px = px0 + wave*16 + pxl, o = m*16 + q*4 + r
  float* xo = xdT + ((size_t)b * HW + px0 + wave * 16 + pxl) * 64 + (q << 2);
#pragma unroll
  for (int m = 0; m < 4; m++)
    *(float4*)(xo + m * 16) = make_float4(acc[m][0], acc[m][1], acc[m][2], acc[m][3]);
  // GN1 partials: g = o>>1 = m*8 + q*2 + (r>>1); reduce over 16 px lanes
  float s[8], sq[8];
#pragma unroll
  for (int m = 0; m < 4; m++)
#pragma unroll
    for (int h = 0; h < 2; h++) {
      float a = acc[m][2 * h] + acc[m][2 * h + 1];
      float qq = acc[m][2 * h] * acc[m][2 * h] + acc[m][2 * h + 1] * acc[m][2 * h + 1];
      s[m * 2 + h] = a; sq[m * 2 + h] = qq;
    }
#pragma unroll
  for (int i = 0; i < 8; i++) {
#pragma unroll
    for (int off = 8; off; off >>= 1) {
      s[i] += __shfl_down(s[i], off, 16);
      sq[i] += __shfl_down(sq[i], off, 16);
    }
  }
  if (pxl == 0) {
#pragma unroll
    for (int i = 0; i < 8; i++) {
      int m = i >> 1, h = i & 1;
      int g = m * 8 + q * 2 + h;
      lds_s[wave][g] = s[i];
      lds_ss[wave][g] = sq[i];
    }
  }
  __syncthreads();
  if (tid < 32) {
    float S = lds_s[0][tid] + lds_s[1][tid] + lds_s[2][tid] + lds_s[3][tid];
    float SS = lds_ss[0][tid] + lds_ss[1][tid] + lds_ss[2][tid] + lds_ss[3][tid];
    int bg = b * 32 + tid;
    ps[(bg * 256 + chunk) * 2] = S;
    ps[(bg * 256 + chunk) * 2 + 1] = SS;
  }
}

// ---- K2: finalize GN stats, block-parallel (grid 128 = one block per bg) ----
__global__ __launch_bounds__(256) void k_gnfin_p(const float* __restrict__ ps, float* __restrict__ mrs,
                                                 int S, float n) {
  int bg = blockIdx.x;
  float s = 0.f, ss = 0.f;
  for (int i = threadIdx.x; i < S; i += 256) { s += ps[(bg * S + i) * 2]; ss += ps[(bg * S + i) * 2 + 1]; }
#pragma unroll
  for (int off = 32; off; off >>= 1) { s += __shfl_down(s, off); ss += __shfl_down(ss, off); }
  __shared__ float ls[4], lss[4];
  int wv = threadIdx.x >> 6;
  if ((threadIdx.x & 63) == 0) { ls[wv] = s; lss[wv] = ss; }
  __syncthreads();
  if (threadIdx.x == 0) {
    float Sa = ls[0] + ls[1] + ls[2] + ls[3];
    float SSa = lss[0] + lss[1] + lss[2] + lss[3];
    float mu = Sa / n;
    float var = SSa / n - mu * mu;
    mrs[bg] = mu;
    mrs[128 + bg] = rsqrtf(var + 1e-5f);
  }
}

// ---- K3: GN1 + ReLU in place on xdT (NHWC, elementwise) ----
__global__ __launch_bounds__(256) void k_gnapply(float* __restrict__ xdT, const float* __restrict__ mrs,
                                                 const float* __restrict__ g1, const float* __restrict__ b1) {
  int i4 = blockIdx.x * 256 + threadIdx.x;
  int b = i4 >> 18;
  int c4 = i4 & 15;
  int g0 = c4 * 2, g1i = c4 * 2 + 1;
  float mu0 = mrs[b * 32 + g0], rs0 = mrs[128 + b * 32 + g0];
  float mu1 = mrs[b * 32 + g1i], rs1 = mrs[128 + b * 32 + g1i];
  float4 gv = *(const float4*)(g1 + c4 * 4);
  float4 bv = *(const float4*)(b1 + c4 * 4);
  float ga0 = gv.x * rs0, be0 = bv.x - mu0 * ga0;
  float ga1 = gv.y * rs0, be1 = bv.y - mu0 * ga1;
  float ga2 = gv.z * rs1, be2 = bv.z - mu1 * ga2;
  float ga3 = gv.w * rs1, be3 = bv.w - mu1 * ga3;
  float4 v = ((const float4*)xdT)[i4];
  v.x = fmaxf(v.x * ga0 + be0, 0.f);
  v.y = fmaxf(v.y * ga1 + be1, 0.f);
  v.z = fmaxf(v.z * ga2 + be2, 0.f);
  v.w = fmaxf(v.w * ga3 + be3, 0.f);
  ((float4*)xdT)[i4] = v;
}

// ---- K4: offsets conv3x3 64->18 via bf16 MFMA (unchanged) ----
__global__ __launch_bounds__(576, 2) void k_off_mfma(const float* __restrict__ xdT,
                                                     const unsigned short* __restrict__ wofBf,
                                                     float* __restrict__ offs) {
  __shared__ unsigned short A[72 * 65 * 8];  // 74,880 B
  int tid = threadIdx.x;
  int bb = blockIdx.x >> 8;
  int px0 = (blockIdx.x & 255) << 6;
  const char* xbt = (const char*)(xdT + (size_t)bb * 64 * HW);
  int wave = tid >> 6;  // tap 0..8
  int lane = tid & 63;
  {
    int q = lane >> 4;
    int ch = lane & 15;
    int co = ch << 4;
    int kcb = wave * 8 + (ch >> 1);
    int wbase = kcb * (65 * 16) + ((ch & 1) << 3);
    int ky = wave / 3 - 1, kx = wave % 3 - 1;
#pragma unroll 2
    for (int g = 0; g < 16; ++g) {
      int src = 4 * g + q;
      int px = px0 + src;
      int sy = (px >> 7) + ky;
      int sx = (px & 127) + kx;
      bool valid = ((unsigned)sy < 128u) && ((unsigned)sx < 128u);
      float4 v = make_float4(0.f, 0.f, 0.f, 0.f);
      if (valid) v = *(const float4*)(xbt + (((sy << 7) + sx) << 8) + co);
      unsigned int r0, r1;
      asm("v_cvt_pk_bf16_f32 %0, %1, %2" : "=v"(r0) : "v"(v.x), "v"(v.y));
      asm("v_cvt_pk_bf16_f32 %0, %1, %2" : "=v"(r1) : "v"(v.z), "v"(v.w));
      *(uint2*)((char*)A + wbase + src * 16) = make_uint2(r0, r1);
    }
  }
  __syncthreads();
  if (wave >= 8) return;
  int n = wave & 1;
  int mh = wave >> 1;
  int r0r = mh * 16 + (lane & 15);
  int kq = lane >> 4;
  const bf16x8* wp = (const bf16x8*)wofBf;
  f32x4 acc = {0.f, 0.f, 0.f, 0.f};
#pragma unroll 3
  for (int kt = 0; kt < 18; kt++) {
    bf16x8 bk = wp[(kt * 2 + n) * 64 + lane];
    int kc = kt * 4 + kq;
    bf16x8 a0 = *(const bf16x8*)((const char*)A + (kc * 65 + r0r) * 16);
    acc = __builtin_amdgcn_mfma_f32_16x16x32_bf16(a0, bk, acc, 0, 0, 0);
  }
  int o = n * 16 + (lane & 15);
  if (o < 18) {
    int prow = mh * 16 + ((lane >> 4) << 2);
    float* op = offs + (size_t)bb * 18 * HW + (size_t)o * HW + px0 + prow;
#pragma unroll
    for (int r = 0; r < 4; r++) op[r] = acc[r];
  }
}

// ---- K5: fused deform + residual + conv2 + GN2 partials; 32-px tiles (38KB LDS -> 3 blk/CU) ----
__global__ __launch_bounds__(576, 4) void k_dcf(const float* __restrict__ xdT,
                                                const float* __restrict__ offs,
                                                const unsigned short* __restrict__ wBf,
                                                const unsigned short* __restrict__ w3Bf,
                                                unsigned short* __restrict__ t3,
                                                float* __restrict__ ps2) {
  __shared__ unsigned short A[72 * 33 * 8];  // 38,016 B
  int tid = threadIdx.x;
  int bb = blockIdx.x >> 9;
  int tileid = blockIdx.x & 511;
  int px0 = tileid << 5;  // 32 px per tile
  const float* xtf = xdT + (size_t)bb * 64 * HW;
  const char* xbt = (const char*)xtf;
  int wave = tid >> 6;
  int lane = tid & 63;

  // geometry for pair (pxl = lane&31, tap = wave); lanes 32-63 duplicate lanes 0-31
  float w00, w01, w10, w11;
  int a00, a01, a10, a11;
  {
    int pxl = lane & 31;
    int px = px0 + pxl;
    int y = px >> 7, xc = px & 127;
    const float* ob = offs + (size_t)bb * 18 * HW + px;
    float dy = ob[(size_t)(2 * wave) * HW];
    float dx = ob[(size_t)(2 * wave + 1) * HW];
    float py = (float)(y + wave / 3 - 1) + dy;
    float pxx = (float)(xc + wave % 3 - 1) + dx;
    float y0f = floorf(py), x0f = floorf(pxx);
    float ay = py - y0f, ax = pxx - x0f;
    int y0 = (int)y0f, x0 = (int)x0f;
    int y1i = y0 + 1, x1i = x0 + 1;
    float by0 = 1.f - ay, bx0 = 1.f - ax;
    bool vy0 = (unsigned)y0 < 128u, vy1 = (unsigned)y1i < 128u;
    bool vx0 = (unsigned)x0 < 128u, vx1 = (unsigned)x1i < 128u;
    w00 = (vy0 && vx0) ? by0 * bx0 : 0.f;
    w01 = (vy0 && vx1) ? by0 * ax : 0.f;
    w10 = (vy1 && vx0) ? ay * bx0 : 0.f;
    w11 = (vy1 && vx1) ? ay * ax : 0.f;
    int iy0 = min(max(y0, 0), 127), iy1 = min(max(y1i, 0), 127);
    int ix0 = min(max(x0, 0), 127), ix1 = min(max(x1i, 0), 127);
    a00 = (iy0 * WIDTH + ix0) << 8;
    a01 = (iy0 * WIDTH + ix1) << 8;
    a10 = (iy1 * WIDTH + ix0) << 8;
    a11 = (iy1 * WIDTH + ix1) << 8;
  }

  // Phase A: gather; 4 pairs/iter, 8 iters; lane = (q = pair-sub, ch = 4-channel chunk)
  {
    int q = lane >> 4;
    int ch = lane & 15;
    int co = ch << 4;
    int kcb = wave * 8 + (ch >> 1);
    int wbase = kcb * (33 * 16) + ((ch & 1) << 3);
#pragma unroll 2
    for (int g = 0; g < 8; ++g) {
      int src = 4 * g + q;  // 0..31
      float j0 = __shfl(w00, src), j1 = __shfl(w01, src);
      float j2 = __shfl(w10, src), j3 = __shfl(w11, src);
      int b0 = __shfl(a00, src), b1 = __shfl(a01, src);
      int b2 = __shfl(a10, src), b3 = __shfl(a11, src);
      float4 v0 = *(const float4*)(xbt + b0 + co);
      float4 v1 = *(const float4*)(xbt + b1 + co);
      float4 v2 = *(const float4*)(xbt + b2 + co);
      float4 v3 = *(const float4*)(xbt + b3 + co);
      float sx = j0 * v0.x + j1 * v1.x + j2 * v2.x + j3 * v3.x;
      float sy = j0 * v0.y + j1 * v1.y + j2 * v2.y + j3 * v3.y;
      float sz = j0 * v0.z + j1 * v1.z + j2 * v2.z + j3 * v3.z;
      float sw = j0 * v0.w + j1 * v1.w + j2 * v2.w + j3 * v3.w;
      unsigned int r0, r1;
      asm("v_cvt_pk_bf16_f32 %0, %1, %2" : "=v"(r0) : "v"(sx), "v"(sy));
      asm("v_cvt_pk_bf16_f32 %0, %1, %2" : "=v"(r1) : "v"(sz), "v"(sw));
      *(uint2*)((char*)A + wbase + src * 16) = make_uint2(r0, r1);
    }
  }
  __syncthreads();

  // Phase B: GEMM1 + residual (waves 0..7): n1 = o-16tile of c-dim, mh = px-16tile
  int n1 = wave & 3;
  int mh = wave >> 2;
  f32x4 acc0 = {0.f, 0.f, 0.f, 0.f};
  if (wave < 8) {
    int r0r = mh * 16 + (lane & 15);
    int kq = lane >> 4;
    const bf16x8* wp = (const bf16x8*)wBf;
#pragma unroll 3
    for (int kt = 0; kt < 18; kt++) {
      bf16x8 bk = wp[(kt * 4 + n1) * 64 + lane];
      int kc = kt * 4 + kq;
      bf16x8 a0 = *(const bf16x8*)((const char*)A + (kc * 33 + r0r) * 16);
      acc0 = __builtin_amdgcn_mfma_f32_16x16x32_bf16(a0, bk, acc0, 0, 0, 0);
    }
    int c = n1 * 16 + (lane & 15);
    int pb = px0 + mh * 16 + ((lane >> 4) << 2);
#pragma unroll
    for (int r = 0; r < 4; r++) acc0[r] += xtf[(size_t)(pb + r) * 64 + c];
  }
  __syncthreads();

  // Phase C: write A2 (bf16 chunk-major [kc=8][row pad33][16B]) into A's head
  if (wave < 8) {
    int c = n1 * 16 + (lane & 15);
    char* base = (char*)A + (c >> 3) * 528 + (c & 7) * 2;
    int pxr = mh * 16 + ((lane >> 4) << 2);
#pragma unroll
    for (int r = 0; r < 4; r++)
      *(unsigned short*)(base + (size_t)(pxr + r) * 16) = f2bf(acc0[r]);
  }
  __syncthreads();
  if (wave >= 8) return;

  // Phase D: GEMM2 (M=32, N=256, K=64): wave = (mh = px-16tile, n1 = n-quad)
  f32x4 cD[4];
#pragma unroll
  for (int ni = 0; ni < 4; ni++) cD[ni] = (f32x4){0.f, 0.f, 0.f, 0.f};
  {
    int kq = lane >> 4;
    const bf16x8* wp2 = (const bf16x8*)w3Bf;
#pragma unroll
    for (int kt = 0; kt < 2; kt++) {
      int kc = kt * 4 + kq;
      bf16x8 aA = *(const bf16x8*)((const char*)A + (size_t)(kc * 33 + mh * 16 + (lane & 15)) * 16);
#pragma unroll
      for (int ni = 0; ni < 4; ni++) {
        int ng = n1 * 4 + ni;
        bf16x8 bk = wp2[(kt * 16 + ng) * 64 + lane];
        cD[ni] = __builtin_amdgcn_mfma_f32_16x16x32_bf16(aA, bk, cD[ni], 0, 0, 0);
      }
    }
  }
  // GN2 partials: group g = (n1*4+ni)*2 + (lane>>3 & 1); reduce px (lane bits 4-5, r) and o bits 0-2
#pragma unroll
  for (int ni = 0; ni < 4; ni++) {
    float s = 0.f, q = 0.f;
#pragma unroll
    for (int r = 0; r < 4; r++) { float v = cD[ni][r]; s += v; q += v * v; }
    s += __shfl_down(s, 32); q += __shfl_down(q, 32);
    s += __shfl_down(s, 16); q += __shfl_down(q, 16);
    s += __shfl_down(s, 4);  q += __shfl_down(q, 4);
    s += __shfl_down(s, 2);  q += __shfl_down(q, 2);
    s += __shfl_down(s, 1);  q += __shfl_down(q, 1);
    if (lane == 0 || lane == 8) {
      int g = (n1 * 4 + ni) * 2 + (lane >> 3);
      int slot = ((bb * 32 + g) * 512 + tileid) * 2 + mh;
      ps2[slot * 2] = s;
      ps2[slot * 2 + 1] = q;
    }
  }
  // bf16 t3 stores (NCHW)
  unsigned short* tb = t3 + (size_t)bb * 256 * HW + px0;
  int mtq = mh * 16 + ((lane >> 4) << 2);
#pragma unroll
  for (int ni = 0; ni < 4; ni++) {
    int o = (n1 * 4 + ni) * 16 + (lane & 15);
    unsigned short* p0 = tb + (size_t)o * HW + mtq;
    unsigned int u0, u1;
    asm("v_cvt_pk_bf16_f32 %0, %1, %2" : "=v"(u0) : "v"(cD[ni][0]), "v"(cD[ni][1]));
    asm("v_cvt_pk_bf16_f32 %0, %1, %2" : "=v"(u1) : "v"(cD[ni][2]), "v"(cD[ni][3]));
    *(uint2*)p0 = make_uint2(u0, u1);
  }
}

// ---- K8: out = relu(gn2(t3_bf16)) + x ----
__global__ __launch_bounds__(256) void k_final(const unsigned short* __restrict__ t3, const float* __restrict__ x,
                                               const float* __restrict__ mrs, const float* __restrict__ g3,
                                               const float* __restrict__ b3, float* __restrict__ out) {
  int i4 = blockIdx.x * 256 + threadIdx.x;
  int b = i4 >> 20;
  int c = (i4 >> 12) & 255;
  int g = c >> 3;
  float mu = mrs[b * 32 + g], rs = mrs[128 + b * 32 + g];
  float ga = g3[c] * rs, be = b3[c] - mu * ga;
  uint2 tv = ((const uint2*)t3)[i4];
  float t0 = __uint_as_float(tv.x << 16);
  float t1 = __uint_as_float(tv.x & 0xffff0000u);
  float t2 = __uint_as_float(tv.y << 16);
  float t3v = __uint_as_float(tv.y & 0xffff0000u);
  float4 xv = ((const float4*)x)[i4];
  float4 r;
  r.x = fmaxf(t0 * ga + be, 0.f) + xv.x;
  r.y = fmaxf(t1 * ga + be, 0.f) + xv.y;
  r.z = fmaxf(t2 * ga + be, 0.f) + xv.z;
  r.w = fmaxf(t3v * ga + be, 0.f) + xv.w;
  ((float4*)out)[i4] = r;
}

extern "C" void kernel_launch(void* const* d_in, const int* in_sizes, int n_in,
                              void* d_out, int out_size, void* d_ws, size_t ws_size,
                              hipStream_t stream) {
  const float* x    = (const float*)d_in[0];
  const float* w1   = (const float*)d_in[1];
  const float* g1   = (const float*)d_in[2];
  const float* b1   = (const float*)d_in[3];
  const float* woff = (const float*)d_in[4];
  const float* wdef = (const float*)d_in[5];
  const float* w3   = (const float*)d_in[6];
  const float* g3   = (const float*)d_in[7];
  const float* b3   = (const float*)d_in[8];
  float* ws = (float*)d_ws;

  float* xdT  = ws;                       // 4,194,304 (NHWC)
  float* offs = xdT + 4194304;            // 1,179,648
  unsigned short* t3 = (unsigned short*)(offs + 1179648);  // 16,777,216 ush = 8,388,608 fl
  float* base = offs + 1179648 + 8388608;
  float* mrs1 = base;                     // 256
  float* mrs2 = mrs1 + 256;               // 256
  unsigned short* wA1f  = (unsigned short*)(mrs2 + 256);                        // 8,192 fl
  unsigned short* wBf   = (unsigned short*)(mrs2 + 256 + 8192);                 // 18,432 fl
  unsigned short* wofBf = (unsigned short*)(mrs2 + 256 + 8192 + 18432);         // 9,216 fl
  unsigned short* w3Bf  = (unsigned short*)(mrs2 + 256 + 8192 + 18432 + 9216);  // 16,384 fl
  float* ps   = mrs2 + 256 + 8192 + 18432 + 9216 + 16384;  // 65,536
  float* ps2  = ps + 65536;               // 262,144
  float* out  = (float*)d_out;

  hipLaunchKernelGGL(k_prep, dim3(144), dim3(256), 0, stream, w1, w3, wdef, woff, wA1f, wBf, wofBf, w3Bf);
  hipLaunchKernelGGL(k_conv1m, dim3(1024), dim3(256), 0, stream, x, wA1f, xdT, ps);
  hipLaunchKernelGGL(k_gnfin_p, dim3(128), dim3(256), 0, stream, ps, mrs1, 256, (float)(2 * HW));
  hipLaunchKernelGGL(k_gnapply, dim3(4096), dim3(256), 0, stream, xdT, mrs1, g1, b1);
  hipLaunchKernelGGL(k_off_mfma, dim3(1024), dim3(576), 0, stream, xdT, wofBf, offs);
  hipLaunchKernelGGL(k_dcf, dim3(2048), dim3(576), 0, stream, xdT, offs, wBf, w3Bf, t3, ps2);
  hipLaunchKernelGGL(k_gnfin_p, dim3(128), dim3(256), 0, stream, ps2, mrs2, 1024, 131072.f);
  hipLaunchKernelGGL(k_final, dim3(16384), dim3(256), 0, stream, t3, x, mrs2, g3, b3, out);
}

// Round 12
// 132.373 us; speedup vs baseline: 1.3123x; 1.0311x over previous
//
#include <hip/hip_runtime.h>

// deformMP: B=4, Cc=256, ci=64, H=W=128, GN groups=32, eps=1e-5
// ws (floats, no aliases, ~51.3 MB):
//   xdT[4.19M] t3bf[8.39M fl-equiv] mrs1[256] mrs2[256]
//   wA1f[8.2K] wBf[18.4K] wofBf[9.2K] w3Bf[16.4K] ps[65.5K] ps2[131K]
// offs lives entirely in LDS inside k_mega (never in HBM).

#define HW 16384
#define WIDTH 128

typedef __attribute__((ext_vector_type(8))) short bf16x8;
typedef __attribute__((ext_vector_type(4))) float f32x4;

__device__ __forceinline__ unsigned short f2bf(float f) {
  unsigned int u = __float_as_uint(f);
  u = (u + 0x7fffu + ((u >> 16) & 1u)) >> 16;  // RNE
  return (unsigned short)u;
}

// ---- K0: weight repack ----
__global__ __launch_bounds__(256) void k_prep(const float* __restrict__ w1, const float* __restrict__ w3,
                                              const float* __restrict__ wdef, const float* __restrict__ woff,
                                              unsigned short* __restrict__ wA1f,
                                              unsigned short* __restrict__ wBf,
                                              unsigned short* __restrict__ wofBf,
                                              unsigned short* __restrict__ w3Bf) {
  int i = blockIdx.x * 256 + threadIdx.x;
  if (i < 16384) {
    // conv1 A-frags: [kt=8][m=4][lane=64][j=8]; elem = w1[o=m*16+(lane&15)][c=kt*32+(lane>>4)*8+j]
    int j = i & 7;
    int lane = (i >> 3) & 63;
    int m = (i >> 9) & 3;
    int kt = i >> 11;
    int o = (m << 4) + (lane & 15);
    int c = kt * 32 + ((lane >> 4) << 3) + j;
    wA1f[i] = f2bf(w1[(size_t)o * 256 + c]);
  }
  if (i < 36864) {
    // deform B-frags: [kt=18][n=4][lane=64][j=8]
    int j = i & 7;
    int lane = (i >> 3) & 63;
    int n = (i >> 9) & 3;
    int kt = i >> 11;
    int kk = kt * 32 + ((lane >> 4) << 3) + j;
    int tap = kk >> 6, c = kk & 63;
    int o = (n << 4) + (lane & 15);
    wBf[i] = f2bf(wdef[(size_t)o * 576 + c * 9 + tap]);
  }
  if (i < 18432) {
    // offs-conv B-frags: [kt=18][n=2][lane=64][j=8]; zero-pad o>=18
    int j = i & 7;
    int lane = (i >> 3) & 63;
    int n = (i >> 9) & 1;
    int kt = i >> 10;
    int kk = kt * 32 + ((lane >> 4) << 3) + j;
    int tap = kk >> 6, c = kk & 63;
    int o = (n << 4) + (lane & 15);
    wofBf[i] = (o < 18) ? f2bf(woff[((size_t)(o * 64 + c)) * 9 + tap]) : (unsigned short)0;
  }
  if (i < 32768) {
    // conv2 B-frags: [kt=2][n=16][lane=64][j=8]
    int j = i & 7;
    int lane = (i >> 3) & 63;
    int n = (i >> 9) & 15;
    int kt = i >> 13;
    int c = kt * 32 + ((lane >> 4) << 3) + j;
    int o = (n << 4) + (lane & 15);
    w3Bf[i] = f2bf(w3[(size_t)o * 64 + c]);
  }
}

// ---- K1: conv1x1 256->64 via bf16 MFMA with LDS-staged x, NHWC write + GN1 partials ----
__global__ __launch_bounds__(256) void k_conv1m(const float* __restrict__ x,
                                                const unsigned short* __restrict__ wA1f,
                                                float* __restrict__ xdT, float* __restrict__ ps) {
  __shared__ unsigned short xs[64][72];  // 9,216 B
  __shared__ float lds_s[4][32], lds_ss[4][32];
  int tid = threadIdx.x;
  int wave = tid >> 6, lane = tid & 63;
  int b = blockIdx.x >> 8;
  int chunk = blockIdx.x & 255;
  int px0 = chunk << 6;
  int pxl = lane & 15, q = lane >> 4;
  const float* xb = x + (size_t)b * 256 * HW + px0;
  const bf16x8* wAp = (const bf16x8*)wA1f;
  f32x4 acc[4];
#pragma unroll
  for (int m = 0; m < 4; m++) acc[m] = (f32x4){0.f, 0.f, 0.f, 0.f};

  for (int cb = 0; cb < 4; cb++) {
    __syncthreads();
#pragma unroll
    for (int r = 0; r < 4; r++) {
      int idx = r * 256 + tid;
      int c = idx >> 4;
      int qd = idx & 15;
      float4 v = *(const float4*)(xb + (size_t)(cb * 64 + c) * HW + qd * 4);
      xs[qd * 4 + 0][c] = f2bf(v.x);
      xs[qd * 4 + 1][c] = f2bf(v.y);
      xs[qd * 4 + 2][c] = f2bf(v.z);
      xs[qd * 4 + 3][c] = f2bf(v.w);
    }
    __syncthreads();
#pragma unroll
    for (int kt = 0; kt < 2; kt++) {
      bf16x8 bfrag = *(const bf16x8*)&xs[wave * 16 + pxl][kt * 32 + q * 8];
      int ktG = cb * 2 + kt;
#pragma unroll
      for (int m = 0; m < 4; m++) {
        bf16x8 af = wAp[(ktG * 4 + m) * 64 + lane];
        acc[m] = __builtin_amdgcn_mfma_f32_16x16x32_bf16(af, bfrag, acc[m], 0, 0, 0);
      }
    }
  }
  float* xo = xdT + ((size_t)b * HW + px0 + wave * 16 + pxl) * 64 + (q << 2);
#pragma unroll
  for (int m = 0; m < 4; m++)
    *(float4*)(xo + m * 16) = make_float4(acc[m][0], acc[m][1], acc[m][2], acc[m][3]);
  float s[8], sq[8];
#pragma unroll
  for (int m = 0; m < 4; m++)
#pragma unroll
    for (int h = 0; h < 2; h++) {
      float a = acc[m][2 * h] + acc[m][2 * h + 1];
      float qq = acc[m][2 * h] * acc[m][2 * h] + acc[m][2 * h + 1] * acc[m][2 * h + 1];
      s[m * 2 + h] = a; sq[m * 2 + h] = qq;
    }
#pragma unroll
  for (int i = 0; i < 8; i++) {
#pragma unroll
    for (int off = 8; off; off >>= 1) {
      s[i] += __shfl_down(s[i], off, 16);
      sq[i] += __shfl_down(sq[i], off, 16);
    }
  }
  if (pxl == 0) {
#pragma unroll
    for (int i = 0; i < 8; i++) {
      int m = i >> 1, h = i & 1;
      int g = m * 8 + q * 2 + h;
      lds_s[wave][g] = s[i];
      lds_ss[wave][g] = sq[i];
    }
  }
  __syncthreads();
  if (tid < 32) {
    float S = lds_s[0][tid] + lds_s[1][tid] + lds_s[2][tid] + lds_s[3][tid];
    float SS = lds_ss[0][tid] + lds_ss[1][tid] + lds_ss[2][tid] + lds_ss[3][tid];
    int bg = b * 32 + tid;
    ps[(bg * 256 + chunk) * 2] = S;
    ps[(bg * 256 + chunk) * 2 + 1] = SS;
  }
}

// ---- K2: finalize GN stats, block-parallel (grid 128 = one block per bg) ----
__global__ __launch_bounds__(256) void k_gnfin_p(const float* __restrict__ ps, float* __restrict__ mrs,
                                                 int S, float n) {
  int bg = blockIdx.x;
  float s = 0.f, ss = 0.f;
  for (int i = threadIdx.x; i < S; i += 256) { s += ps[(bg * S + i) * 2]; ss += ps[(bg * S + i) * 2 + 1]; }
#pragma unroll
  for (int off = 32; off; off >>= 1) { s += __shfl_down(s, off); ss += __shfl_down(ss, off); }
  __shared__ float ls[4], lss[4];
  int wv = threadIdx.x >> 6;
  if ((threadIdx.x & 63) == 0) { ls[wv] = s; lss[wv] = ss; }
  __syncthreads();
  if (threadIdx.x == 0) {
    float Sa = ls[0] + ls[1] + ls[2] + ls[3];
    float SSa = lss[0] + lss[1] + lss[2] + lss[3];
    float mu = Sa / n;
    float var = SSa / n - mu * mu;
    mrs[bg] = mu;
    mrs[128 + bg] = rsqrtf(var + 1e-5f);
  }
}

// ---- K3: GN1 + ReLU in place on xdT (NHWC, elementwise) ----
__global__ __launch_bounds__(256) void k_gnapply(float* __restrict__ xdT, const float* __restrict__ mrs,
                                                 const float* __restrict__ g1, const float* __restrict__ b1) {
  int i4 = blockIdx.x * 256 + threadIdx.x;
  int b = i4 >> 18;
  int c4 = i4 & 15;
  int g0 = c4 * 2, g1i = c4 * 2 + 1;
  float mu0 = mrs[b * 32 + g0], rs0 = mrs[128 + b * 32 + g0];
  float mu1 = mrs[b * 32 + g1i], rs1 = mrs[128 + b * 32 + g1i];
  float4 gv = *(const float4*)(g1 + c4 * 4);
  float4 bv = *(const float4*)(b1 + c4 * 4);
  float ga0 = gv.x * rs0, be0 = bv.x - mu0 * ga0;
  float ga1 = gv.y * rs0, be1 = bv.y - mu0 * ga1;
  float ga2 = gv.z * rs1, be2 = bv.z - mu1 * ga2;
  float ga3 = gv.w * rs1, be3 = bv.w - mu1 * ga3;
  float4 v = ((const float4*)xdT)[i4];
  v.x = fmaxf(v.x * ga0 + be0, 0.f);
  v.y = fmaxf(v.y * ga1 + be1, 0.f);
  v.z = fmaxf(v.z * ga2 + be2, 0.f);
  v.w = fmaxf(v.w * ga3 + be3, 0.f);
  ((float4*)xdT)[i4] = v;
}

// ---- K5: MEGA — offsets conv + deform conv + residual + conv2 + GN2 partials, one kernel.
// 64-px tile, 9 waves. P0: fixed-tap im2col -> A. P1: off-GEMM -> offsL (LDS, never HBM).
// P2/P3: geometry from offsL + bilinear gather -> A (overwrite). P4: GEMM1 + residual.
// P5: A2 bf16. P6: GEMM2 + GN2 partials + bf16 t3 stores.
__global__ __launch_bounds__(576, 4) void k_mega(const float* __restrict__ xdT,
                                                 const unsigned short* __restrict__ wofBf,
                                                 const unsigned short* __restrict__ wBf,
                                                 const unsigned short* __restrict__ w3Bf,
                                                 unsigned short* __restrict__ t3,
                                                 float* __restrict__ ps2) {
  __shared__ unsigned short A[72 * 65 * 8];  // 74,880 B
  __shared__ float offsL[64 * 18];           // 4,608 B
  int tid = threadIdx.x;
  int bb = blockIdx.x >> 8;
  int tileid = blockIdx.x & 255;
  int px0 = tileid << 6;
  const float* xtf = xdT + (size_t)bb * 64 * HW;
  const char* xbt = (const char*)xtf;
  int wave = tid >> 6;  // 0..8 (= tap in build phases)
  int lane = tid & 63;
  int q = lane >> 4;
  int ch = lane & 15;
  int co = ch << 4;
  int kcb = wave * 8 + (ch >> 1);
  int wbase = kcb * (65 * 16) + ((ch & 1) << 3);

  // ---- P0: fixed-tap im2col build (tap = wave) ----
  {
    int ky = wave / 3 - 1, kx = wave % 3 - 1;
#pragma unroll 2
    for (int g = 0; g < 16; ++g) {
      int src = 4 * g + q;
      int px = px0 + src;
      int sy = (px >> 7) + ky;
      int sx = (px & 127) + kx;
      bool valid = ((unsigned)sy < 128u) && ((unsigned)sx < 128u);
      float4 v = make_float4(0.f, 0.f, 0.f, 0.f);
      if (valid) v = *(const float4*)(xbt + (((sy << 7) + sx) << 8) + co);
      unsigned int r0, r1;
      asm("v_cvt_pk_bf16_f32 %0, %1, %2" : "=v"(r0) : "v"(v.x), "v"(v.y));
      asm("v_cvt_pk_bf16_f32 %0, %1, %2" : "=v"(r1) : "v"(v.z), "v"(v.w));
      *(uint2*)((char*)A + wbase + src * 16) = make_uint2(r0, r1);
    }
  }
  __syncthreads();

  // ---- P1: offsets GEMM (waves 0..7): D[64px][18] -> offsL ----
  if (wave < 8) {
    int n = wave & 1;
    int mh1 = wave >> 1;
    int r0r = mh1 * 16 + (lane & 15);
    int kq = lane >> 4;
    const bf16x8* wp = (const bf16x8*)wofBf;
    f32x4 acc = {0.f, 0.f, 0.f, 0.f};
#pragma unroll 3
    for (int kt = 0; kt < 18; kt++) {
      bf16x8 bk = wp[(kt * 2 + n) * 64 + lane];
      int kc = kt * 4 + kq;
      bf16x8 a0 = *(const bf16x8*)((const char*)A + (kc * 65 + r0r) * 16);
      acc = __builtin_amdgcn_mfma_f32_16x16x32_bf16(a0, bk, acc, 0, 0, 0);
    }
    int o = n * 16 + (lane & 15);
    if (o < 18) {
      int prow = mh1 * 16 + ((lane >> 4) << 2);
#pragma unroll
      for (int r = 0; r < 4; r++) offsL[(prow + r) * 18 + o] = acc[r];
    }
  }
  __syncthreads();

  // ---- P2: geometry from offsL (pxl = lane, tap = wave) ----
  float w00, w01, w10, w11;
  int a00, a01, a10, a11;
  {
    int px = px0 + lane;
    int y = px >> 7, xc = px & 127;
    float dy = offsL[lane * 18 + 2 * wave];
    float dx = offsL[lane * 18 + 2 * wave + 1];
    float py = (float)(y + wave / 3 - 1) + dy;
    float pxx = (float)(xc + wave % 3 - 1) + dx;
    float y0f = floorf(py), x0f = floorf(pxx);
    float ay = py - y0f, ax = pxx - x0f;
    int y0 = (int)y0f, x0 = (int)x0f;
    int y1i = y0 + 1, x1i = x0 + 1;
    float by0 = 1.f - ay, bx0 = 1.f - ax;
    bool vy0 = (unsigned)y0 < 128u, vy1 = (unsigned)y1i < 128u;
    bool vx0 = (unsigned)x0 < 128u, vx1 = (unsigned)x1i < 128u;
    w00 = (vy0 && vx0) ? by0 * bx0 : 0.f;
    w01 = (vy0 && vx1) ? by0 * ax : 0.f;
    w10 = (vy1 && vx0) ? ay * bx0 : 0.f;
    w11 = (vy1 && vx1) ? ay * ax : 0.f;
    int iy0 = min(max(y0, 0), 127), iy1 = min(max(y1i, 0), 127);
    int ix0 = min(max(x0, 0), 127), ix1 = min(max(x1i, 0), 127);
    a00 = (iy0 * WIDTH + ix0) << 8;
    a01 = (iy0 * WIDTH + ix1) << 8;
    a10 = (iy1 * WIDTH + ix0) << 8;
    a11 = (iy1 * WIDTH + ix1) << 8;
  }

  // ---- P3: bilinear gather -> A (overwrite; P1 consumed A before the barrier) ----
  {
#pragma unroll 2
    for (int g = 0; g < 16; ++g) {
      int src = 4 * g + q;
      float j0 = __shfl(w00, src), j1 = __shfl(w01, src);
      float j2 = __shfl(w10, src), j3 = __shfl(w11, src);
      int b0 = __shfl(a00, src), b1 = __shfl(a01, src);
      int b2 = __shfl(a10, src), b3 = __shfl(a11, src);
      float4 v0 = *(const float4*)(xbt + b0 + co);
      float4 v1 = *(const float4*)(xbt + b1 + co);
      float4 v2 = *(const float4*)(xbt + b2 + co);
      float4 v3 = *(const float4*)(xbt + b3 + co);
      float sx = j0 * v0.x + j1 * v1.x + j2 * v2.x + j3 * v3.x;
      float sy = j0 * v0.y + j1 * v1.y + j2 * v2.y + j3 * v3.y;
      float sz = j0 * v0.z + j1 * v1.z + j2 * v2.z + j3 * v3.z;
      float sw = j0 * v0.w + j1 * v1.w + j2 * v2.w + j3 * v3.w;
      unsigned int r0, r1;
      asm("v_cvt_pk_bf16_f32 %0, %1, %2" : "=v"(r0) : "v"(sx), "v"(sy));
      asm("v_cvt_pk_bf16_f32 %0, %1, %2" : "=v"(r1) : "v"(sz), "v"(sw));
      *(uint2*)((char*)A + wbase + src * 16) = make_uint2(r0, r1);
    }
  }
  __syncthreads();

  // ---- P4: GEMM1 + residual (waves 0..7) ----
  int n1 = wave & 3;
  int mh = wave >> 2;
  f32x4 acc0 = {0.f, 0.f, 0.f, 0.f};
  f32x4 acc1 = {0.f, 0.f, 0.f, 0.f};
  if (wave < 8) {
    int r0r = mh * 32 + (lane & 15);
    int kq = lane >> 4;
    const bf16x8* wp = (const bf16x8*)wBf;
#pragma unroll 3
    for (int kt = 0; kt < 18; kt++) {
      bf16x8 bk = wp[(kt * 4 + n1) * 64 + lane];
      int kc = kt * 4 + kq;
      bf16x8 a0 = *(const bf16x8*)((const char*)A + (kc * 65 + r0r) * 16);
      bf16x8 a1 = *(const bf16x8*)((const char*)A + (kc * 65 + r0r + 16) * 16);
      acc0 = __builtin_amdgcn_mfma_f32_16x16x32_bf16(a0, bk, acc0, 0, 0, 0);
      acc1 = __builtin_amdgcn_mfma_f32_16x16x32_bf16(a1, bk, acc1, 0, 0, 0);
    }
    int c = n1 * 16 + (lane & 15);
    int pb = px0 + mh * 32 + ((lane >> 4) << 2);
#pragma unroll
    for (int r = 0; r < 4; r++) {
      acc0[r] += xtf[(size_t)(pb + r) * 64 + c];
      acc1[r] += xtf[(size_t)(pb + 16 + r) * 64 + c];
    }
  }
  __syncthreads();

  // ---- P5: write A2 (bf16 chunk-major [kc=8][row pad65][16B]) into A's head ----
  if (wave < 8) {
    int c = n1 * 16 + (lane & 15);
    char* base = (char*)A + (c >> 3) * 1040 + (c & 7) * 2;
    int pxr = mh * 32 + ((lane >> 4) << 2);
#pragma unroll
    for (int r = 0; r < 4; r++) {
      *(unsigned short*)(base + (size_t)(pxr + r) * 16) = f2bf(acc0[r]);
      *(unsigned short*)(base + (size_t)(pxr + 16 + r) * 16) = f2bf(acc1[r]);
    }
  }
  __syncthreads();
  if (wave >= 8) return;

  // ---- P6: GEMM2 (M=64, N=256, K=64) + GN2 partials + bf16 t3 ----
  f32x4 cA[4], cB[4];
#pragma unroll
  for (int ni = 0; ni < 4; ni++) {
    cA[ni] = (f32x4){0.f, 0.f, 0.f, 0.f};
    cB[ni] = (f32x4){0.f, 0.f, 0.f, 0.f};
  }
  {
    int kq = lane >> 4;
    int mt0 = (wave >> 2) * 2;
    const bf16x8* wp2 = (const bf16x8*)w3Bf;
#pragma unroll
    for (int kt = 0; kt < 2; kt++) {
      int kc = kt * 4 + kq;
      bf16x8 aA = *(const bf16x8*)((const char*)A + (size_t)(kc * 65 + mt0 * 16 + (lane & 15)) * 16);
      bf16x8 aB = *(const bf16x8*)((const char*)A + (size_t)(kc * 65 + (mt0 + 1) * 16 + (lane & 15)) * 16);
#pragma unroll
      for (int ni = 0; ni < 4; ni++) {
        int ng = n1 * 4 + ni;
        bf16x8 bk = wp2[(kt * 16 + ng) * 64 + lane];
        cA[ni] = __builtin_amdgcn_mfma_f32_16x16x32_bf16(aA, bk, cA[ni], 0, 0, 0);
        cB[ni] = __builtin_amdgcn_mfma_f32_16x16x32_bf16(aB, bk, cB[ni], 0, 0, 0);
      }
    }
  }
#pragma unroll
  for (int ni = 0; ni < 4; ni++) {
    float s = 0.f, qq = 0.f;
#pragma unroll
    for (int r = 0; r < 4; r++) {
      float v0 = cA[ni][r], v1 = cB[ni][r];
      s += v0 + v1; qq += v0 * v0 + v1 * v1;
    }
    s += __shfl_down(s, 32); qq += __shfl_down(qq, 32);
    s += __shfl_down(s, 16); qq += __shfl_down(qq, 16);
    s += __shfl_down(s, 4);  qq += __shfl_down(qq, 4);
    s += __shfl_down(s, 2);  qq += __shfl_down(qq, 2);
    s += __shfl_down(s, 1);  qq += __shfl_down(qq, 1);
    if (lane == 0 || lane == 8) {
      int g = (n1 * 4 + ni) * 2 + (lane >> 3);
      int slot = ((bb * 32 + g) * 256 + tileid) * 2 + (wave >> 2);
      ps2[slot * 2] = s;
      ps2[slot * 2 + 1] = qq;
    }
  }
  unsigned short* tb = t3 + (size_t)bb * 256 * HW + px0;
  int mtq = (wave >> 2) * 32 + ((lane >> 4) << 2);
#pragma unroll
  for (int ni = 0; ni < 4; ni++) {
    int o = (n1 * 4 + ni) * 16 + (lane & 15);
    unsigned short* p0 = tb + (size_t)o * HW + mtq;
    unsigned int u0, u1, u2, u3;
    asm("v_cvt_pk_bf16_f32 %0, %1, %2" : "=v"(u0) : "v"(cA[ni][0]), "v"(cA[ni][1]));
    asm("v_cvt_pk_bf16_f32 %0, %1, %2" : "=v"(u1) : "v"(cA[ni][2]), "v"(cA[ni][3]));
    asm("v_cvt_pk_bf16_f32 %0, %1, %2" : "=v"(u2) : "v"(cB[ni][0]), "v"(cB[ni][1]));
    asm("v_cvt_pk_bf16_f32 %0, %1, %2" : "=v"(u3) : "v"(cB[ni][2]), "v"(cB[ni][3]));
    *(uint2*)p0 = make_uint2(u0, u1);
    *(uint2*)(p0 + 16) = make_uint2(u2, u3);
  }
}

// ---- K8: out = relu(gn2(t3_bf16)) + x ----
__global__ __launch_bounds__(256) void k_final(const unsigned short* __restrict__ t3, const float* __restrict__ x,
                                               const float* __restrict__ mrs, const float* __restrict__ g3,
                                               const float* __restrict__ b3, float* __restrict__ out) {
  int i4 = blockIdx.x * 256 + threadIdx.x;
  int b = i4 >> 20;
  int c = (i4 >> 12) & 255;
  int g = c >> 3;
  float mu = mrs[b * 32 + g], rs = mrs[128 + b * 32 + g];
  float ga = g3[c] * rs, be = b3[c] - mu * ga;
  uint2 tv = ((const uint2*)t3)[i4];
  float t0 = __uint_as_float(tv.x << 16);
  float t1 = __uint_as_float(tv.x & 0xffff0000u);
  float t2 = __uint_as_float(tv.y << 16);
  float t3v = __uint_as_float(tv.y & 0xffff0000u);
  float4 xv = ((const float4*)x)[i4];
  float4 r;
  r.x = fmaxf(t0 * ga + be, 0.f) + xv.x;
  r.y = fmaxf(t1 * ga + be, 0.f) + xv.y;
  r.z = fmaxf(t2 * ga + be, 0.f) + xv.z;
  r.w = fmaxf(t3v * ga + be, 0.f) + xv.w;
  ((float4*)out)[i4] = r;
}

extern "C" void kernel_launch(void* const* d_in, const int* in_sizes, int n_in,
                              void* d_out, int out_size, void* d_ws, size_t ws_size,
                              hipStream_t stream) {
  const float* x    = (const float*)d_in[0];
  const float* w1   = (const float*)d_in[1];
  const float* g1   = (const float*)d_in[2];
  const float* b1   = (const float*)d_in[3];
  const float* woff = (const float*)d_in[4];
  const float* wdef = (const float*)d_in[5];
  const float* w3   = (const float*)d_in[6];
  const float* g3   = (const float*)d_in[7];
  const float* b3   = (const float*)d_in[8];
  float* ws = (float*)d_ws;

  float* xdT  = ws;                       // 4,194,304 (NHWC)
  unsigned short* t3 = (unsigned short*)(xdT + 4194304);  // 16,777,216 ush = 8,388,608 fl
  float* base = xdT + 4194304 + 8388608;
  float* mrs1 = base;                     // 256
  float* mrs2 = mrs1 + 256;               // 256
  unsigned short* wA1f  = (unsigned short*)(mrs2 + 256);                        // 8,192 fl
  unsigned short* wBf   = (unsigned short*)(mrs2 + 256 + 8192);                 // 18,432 fl
  unsigned short* wofBf = (unsigned short*)(mrs2 + 256 + 8192 + 18432);         // 9,216 fl
  unsigned short* w3Bf  = (unsigned short*)(mrs2 + 256 + 8192 + 18432 + 9216);  // 16,384 fl
  float* ps   = mrs2 + 256 + 8192 + 18432 + 9216 + 16384;  // 65,536
  float* ps2  = ps + 65536;               // 131,072
  float* out  = (float*)d_out;

  hipLaunchKernelGGL(k_prep, dim3(144), dim3(256), 0, stream, w1, w3, wdef, woff, wA1f, wBf, wofBf, w3Bf);
  hipLaunchKernelGGL(k_conv1m, dim3(1024), dim3(256), 0, stream, x, wA1f, xdT, ps);
  hipLaunchKernelGGL(k_gnfin_p, dim3(128), dim3(256), 0, stream, ps, mrs1, 256, (float)(2 * HW));
  hipLaunchKernelGGL(k_gnapply, dim3(4096), dim3(256), 0, stream, xdT, mrs1, g1, b1);
  hipLaunchKernelGGL(k_mega, dim3(1024), dim3(576), 0, stream, xdT, wofBf, wBf, w3Bf, t3, ps2);
  hipLaunchKernelGGL(k_gnfin_p, dim3(128), dim3(256), 0, stream, ps2, mrs2, 512, 131072.f);
  hipLaunchKernelGGL(k_final, dim3(16384), dim3(256), 0, stream, t3, x, mrs2, g3, b3, out);
}

// Round 13
// 128.239 us; speedup vs baseline: 1.3546x; 1.0322x over previous
//
#include <hip/hip_runtime.h>

// deformMP: B=4, Cc=256, ci=64, H=W=128, GN groups=32, eps=1e-5
// ws (floats, no aliases, ~51.3 MB):
//   xdT[4.19M] t3bf[8.39M fl-equiv] mrs1[256] mrs2[256]
//   wA1f[8.2K] wBf[18.4K] wofBf[9.2K] w3Bf[16.4K] ps[65.5K] ps2[131K]
// offs lives entirely in LDS inside k_mega. k_mega K-splits by channel half
// (c<32 = even kt, c>=32 = odd kt) so A is 37.4KB -> 42KB LDS -> 3 blocks/CU.

#define HW 16384
#define WIDTH 128

typedef __attribute__((ext_vector_type(8))) short bf16x8;
typedef __attribute__((ext_vector_type(4))) float f32x4;

__device__ __forceinline__ unsigned short f2bf(float f) {
  unsigned int u = __float_as_uint(f);
  u = (u + 0x7fffu + ((u >> 16) & 1u)) >> 16;  // RNE
  return (unsigned short)u;
}

// ---- K0: weight repack (unchanged) ----
__global__ __launch_bounds__(256) void k_prep(const float* __restrict__ w1, const float* __restrict__ w3,
                                              const float* __restrict__ wdef, const float* __restrict__ woff,
                                              unsigned short* __restrict__ wA1f,
                                              unsigned short* __restrict__ wBf,
                                              unsigned short* __restrict__ wofBf,
                                              unsigned short* __restrict__ w3Bf) {
  int i = blockIdx.x * 256 + threadIdx.x;
  if (i < 16384) {
    int j = i & 7;
    int lane = (i >> 3) & 63;
    int m = (i >> 9) & 3;
    int kt = i >> 11;
    int o = (m << 4) + (lane & 15);
    int c = kt * 32 + ((lane >> 4) << 3) + j;
    wA1f[i] = f2bf(w1[(size_t)o * 256 + c]);
  }
  if (i < 36864) {
    int j = i & 7;
    int lane = (i >> 3) & 63;
    int n = (i >> 9) & 3;
    int kt = i >> 11;
    int kk = kt * 32 + ((lane >> 4) << 3) + j;
    int tap = kk >> 6, c = kk & 63;
    int o = (n << 4) + (lane & 15);
    wBf[i] = f2bf(wdef[(size_t)o * 576 + c * 9 + tap]);
  }
  if (i < 18432) {
    int j = i & 7;
    int lane = (i >> 3) & 63;
    int n = (i >> 9) & 1;
    int kt = i >> 10;
    int kk = kt * 32 + ((lane >> 4) << 3) + j;
    int tap = kk >> 6, c = kk & 63;
    int o = (n << 4) + (lane & 15);
    wofBf[i] = (o < 18) ? f2bf(woff[((size_t)(o * 64 + c)) * 9 + tap]) : (unsigned short)0;
  }
  if (i < 32768) {
    int j = i & 7;
    int lane = (i >> 3) & 63;
    int n = (i >> 9) & 15;
    int kt = i >> 13;
    int c = kt * 32 + ((lane >> 4) << 3) + j;
    int o = (n << 4) + (lane & 15);
    w3Bf[i] = f2bf(w3[(size_t)o * 64 + c]);
  }
}

// ---- K1: conv1x1 256->64 via bf16 MFMA with LDS-staged x, NHWC write + GN1 partials ----
__global__ __launch_bounds__(256) void k_conv1m(const float* __restrict__ x,
                                                const unsigned short* __restrict__ wA1f,
                                                float* __restrict__ xdT, float* __restrict__ ps) {
  __shared__ unsigned short xs[64][72];
  __shared__ float lds_s[4][32], lds_ss[4][32];
  int tid = threadIdx.x;
  int wave = tid >> 6, lane = tid & 63;
  int b = blockIdx.x >> 8;
  int chunk = blockIdx.x & 255;
  int px0 = chunk << 6;
  int pxl = lane & 15, q = lane >> 4;
  const float* xb = x + (size_t)b * 256 * HW + px0;
  const bf16x8* wAp = (const bf16x8*)wA1f;
  f32x4 acc[4];
#pragma unroll
  for (int m = 0; m < 4; m++) acc[m] = (f32x4){0.f, 0.f, 0.f, 0.f};

  for (int cb = 0; cb < 4; cb++) {
    __syncthreads();
#pragma unroll
    for (int r = 0; r < 4; r++) {
      int idx = r * 256 + tid;
      int c = idx >> 4;
      int qd = idx & 15;
      float4 v = *(const float4*)(xb + (size_t)(cb * 64 + c) * HW + qd * 4);
      xs[qd * 4 + 0][c] = f2bf(v.x);
      xs[qd * 4 + 1][c] = f2bf(v.y);
      xs[qd * 4 + 2][c] = f2bf(v.z);
      xs[qd * 4 + 3][c] = f2bf(v.w);
    }
    __syncthreads();
#pragma unroll
    for (int kt = 0; kt < 2; kt++) {
      bf16x8 bfrag = *(const bf16x8*)&xs[wave * 16 + pxl][kt * 32 + q * 8];
      int ktG = cb * 2 + kt;
#pragma unroll
      for (int m = 0; m < 4; m++) {
        bf16x8 af = wAp[(ktG * 4 + m) * 64 + lane];
        acc[m] = __builtin_amdgcn_mfma_f32_16x16x32_bf16(af, bfrag, acc[m], 0, 0, 0);
      }
    }
  }
  float* xo = xdT + ((size_t)b * HW + px0 + wave * 16 + pxl) * 64 + (q << 2);
#pragma unroll
  for (int m = 0; m < 4; m++)
    *(float4*)(xo + m * 16) = make_float4(acc[m][0], acc[m][1], acc[m][2], acc[m][3]);
  float s[8], sq[8];
#pragma unroll
  for (int m = 0; m < 4; m++)
#pragma unroll
    for (int h = 0; h < 2; h++) {
      float a = acc[m][2 * h] + acc[m][2 * h + 1];
      float qq = acc[m][2 * h] * acc[m][2 * h] + acc[m][2 * h + 1] * acc[m][2 * h + 1];
      s[m * 2 + h] = a; sq[m * 2 + h] = qq;
    }
#pragma unroll
  for (int i = 0; i < 8; i++) {
#pragma unroll
    for (int off = 8; off; off >>= 1) {
      s[i] += __shfl_down(s[i], off, 16);
      sq[i] += __shfl_down(sq[i], off, 16);
    }
  }
  if (pxl == 0) {
#pragma unroll
    for (int i = 0; i < 8; i++) {
      int m = i >> 1, h = i & 1;
      int g = m * 8 + q * 2 + h;
      lds_s[wave][g] = s[i];
      lds_ss[wave][g] = sq[i];
    }
  }
  __syncthreads();
  if (tid < 32) {
    float S = lds_s[0][tid] + lds_s[1][tid] + lds_s[2][tid] + lds_s[3][tid];
    float SS = lds_ss[0][tid] + lds_ss[1][tid] + lds_ss[2][tid] + lds_ss[3][tid];
    int bg = b * 32 + tid;
    ps[(bg * 256 + chunk) * 2] = S;
    ps[(bg * 256 + chunk) * 2 + 1] = SS;
  }
}

// ---- K2: finalize GN stats, block-parallel ----
__global__ __launch_bounds__(256) void k_gnfin_p(const float* __restrict__ ps, float* __restrict__ mrs,
                                                 int S, float n) {
  int bg = blockIdx.x;
  float s = 0.f, ss = 0.f;
  for (int i = threadIdx.x; i < S; i += 256) { s += ps[(bg * S + i) * 2]; ss += ps[(bg * S + i) * 2 + 1]; }
#pragma unroll
  for (int off = 32; off; off >>= 1) { s += __shfl_down(s, off); ss += __shfl_down(ss, off); }
  __shared__ float ls[4], lss[4];
  int wv = threadIdx.x >> 6;
  if ((threadIdx.x & 63) == 0) { ls[wv] = s; lss[wv] = ss; }
  __syncthreads();
  if (threadIdx.x == 0) {
    float Sa = ls[0] + ls[1] + ls[2] + ls[3];
    float SSa = lss[0] + lss[1] + lss[2] + lss[3];
    float mu = Sa / n;
    float var = SSa / n - mu * mu;
    mrs[bg] = mu;
    mrs[128 + bg] = rsqrtf(var + 1e-5f);
  }
}

// ---- K3: GN1 + ReLU in place on xdT (NHWC, elementwise) ----
__global__ __launch_bounds__(256) void k_gnapply(float* __restrict__ xdT, const float* __restrict__ mrs,
                                                 const float* __restrict__ g1, const float* __restrict__ b1) {
  int i4 = blockIdx.x * 256 + threadIdx.x;
  int b = i4 >> 18;
  int c4 = i4 & 15;
  int g0 = c4 * 2, g1i = c4 * 2 + 1;
  float mu0 = mrs[b * 32 + g0], rs0 = mrs[128 + b * 32 + g0];
  float mu1 = mrs[b * 32 + g1i], rs1 = mrs[128 + b * 32 + g1i];
  float4 gv = *(const float4*)(g1 + c4 * 4);
  float4 bv = *(const float4*)(b1 + c4 * 4);
  float ga0 = gv.x * rs0, be0 = bv.x - mu0 * ga0;
  float ga1 = gv.y * rs0, be1 = bv.y - mu0 * ga1;
  float ga2 = gv.z * rs1, be2 = bv.z - mu1 * ga2;
  float ga3 = gv.w * rs1, be3 = bv.w - mu1 * ga3;
  float4 v = ((const float4*)xdT)[i4];
  v.x = fmaxf(v.x * ga0 + be0, 0.f);
  v.y = fmaxf(v.y * ga1 + be1, 0.f);
  v.z = fmaxf(v.z * ga2 + be2, 0.f);
  v.w = fmaxf(v.w * ga3 + be3, 0.f);
  ((float4*)xdT)[i4] = v;
}

// ---- K5: MEGA v2 — off-conv + deform + residual + conv2 + GN2, K-split by channel half.
// A[36 kc][65 row][16B] = 37.4KB; + offsL 4.6KB = 42KB LDS -> 3 blocks/CU.
// Half h covers channels h*32..h*32+31 == global kt = 2*tap+h. Accumulators carry
// across halves in registers. Build lanes: (q8 = lane>>3 pair-sub, ch8 = lane&7 chunk).
__global__ __launch_bounds__(576, 7) void k_mega(const float* __restrict__ xdT,
                                                 const unsigned short* __restrict__ wofBf,
                                                 const unsigned short* __restrict__ wBf,
                                                 const unsigned short* __restrict__ w3Bf,
                                                 unsigned short* __restrict__ t3,
                                                 float* __restrict__ ps2) {
  __shared__ unsigned short A[36 * 65 * 8];  // 37,440 B
  __shared__ float offsL[64 * 18];           // 4,608 B
  int tid = threadIdx.x;
  int bb = blockIdx.x >> 8;
  int tileid = blockIdx.x & 255;
  int px0 = tileid << 6;
  const float* xtf = xdT + (size_t)bb * 64 * HW;
  const char* xbt = (const char*)xtf;
  int wave = tid >> 6;  // 0..8 = tap in build phases
  int lane = tid & 63;
  int q8 = lane >> 3;   // pair-sub 0..7
  int ch8 = lane & 7;   // 4-channel chunk within 32-ch half
  int kcbyte = (wave * 4 + (ch8 >> 1)) * 1040 + ((ch8 & 1) << 3);
  int kq = lane >> 4;

  // ---- P0/P1: fixed-tap build + off-GEMM, two channel halves ----
  f32x4 aoff = {0.f, 0.f, 0.f, 0.f};
  {
    int ky = wave / 3 - 1, kx = wave % 3 - 1;
    int n2 = wave & 1;
    int mh1 = wave >> 1;
    int r1 = mh1 * 16 + (lane & 15);
    for (int h = 0; h < 2; ++h) {
      int co = (h << 7) + (ch8 << 4);
#pragma unroll 2
      for (int g = 0; g < 8; ++g) {
        int src = 8 * g + q8;
        int px = px0 + src;
        int sy = (px >> 7) + ky;
        int sx = (px & 127) + kx;
        bool valid = ((unsigned)sy < 128u) && ((unsigned)sx < 128u);
        float4 v = make_float4(0.f, 0.f, 0.f, 0.f);
        if (valid) v = *(const float4*)(xbt + (((sy << 7) + sx) << 8) + co);
        unsigned int u0, u1;
        asm("v_cvt_pk_bf16_f32 %0, %1, %2" : "=v"(u0) : "v"(v.x), "v"(v.y));
        asm("v_cvt_pk_bf16_f32 %0, %1, %2" : "=v"(u1) : "v"(v.z), "v"(v.w));
        *(uint2*)((char*)A + kcbyte + src * 16) = make_uint2(u0, u1);
      }
      __syncthreads();
      if (wave < 8) {
        const bf16x8* wp = (const bf16x8*)wofBf;
        __builtin_amdgcn_s_setprio(1);
#pragma unroll
        for (int tap = 0; tap < 9; ++tap) {
          bf16x8 bk = wp[((2 * tap + h) * 2 + n2) * 64 + lane];
          bf16x8 a0 = *(const bf16x8*)((const char*)A + ((tap * 4 + kq) * 65 + r1) * 16);
          aoff = __builtin_amdgcn_mfma_f32_16x16x32_bf16(a0, bk, aoff, 0, 0, 0);
        }
        __builtin_amdgcn_s_setprio(0);
      }
      __syncthreads();
    }
    if (wave < 8) {
      int o = n2 * 16 + (lane & 15);
      if (o < 18) {
        int prow = mh1 * 16 + ((lane >> 4) << 2);
#pragma unroll
        for (int r = 0; r < 4; r++) offsL[(prow + r) * 18 + o] = aoff[r];
      }
    }
  }
  __syncthreads();

  // ---- P2: geometry from offsL (pxl = lane, tap = wave) ----
  float w00, w01, w10, w11;
  int a00, a01, a10, a11;
  {
    int px = px0 + lane;
    int y = px >> 7, xc = px & 127;
    float dy = offsL[lane * 18 + 2 * wave];
    float dx = offsL[lane * 18 + 2 * wave + 1];
    float py = (float)(y + wave / 3 - 1) + dy;
    float pxx = (float)(xc + wave % 3 - 1) + dx;
    float y0f = floorf(py), x0f = floorf(pxx);
    float ay = py - y0f, ax = pxx - x0f;
    int y0 = (int)y0f, x0 = (int)x0f;
    int y1i = y0 + 1, x1i = x0 + 1;
    float by0 = 1.f - ay, bx0 = 1.f - ax;
    bool vy0 = (unsigned)y0 < 128u, vy1 = (unsigned)y1i < 128u;
    bool vx0 = (unsigned)x0 < 128u, vx1 = (unsigned)x1i < 128u;
    w00 = (vy0 && vx0) ? by0 * bx0 : 0.f;
    w01 = (vy0 && vx1) ? by0 * ax : 0.f;
    w10 = (vy1 && vx0) ? ay * bx0 : 0.f;
    w11 = (vy1 && vx1) ? ay * ax : 0.f;
    int iy0 = min(max(y0, 0), 127), iy1 = min(max(y1i, 0), 127);
    int ix0 = min(max(x0, 0), 127), ix1 = min(max(x1i, 0), 127);
    a00 = (iy0 * WIDTH + ix0) << 8;
    a01 = (iy0 * WIDTH + ix1) << 8;
    a10 = (iy1 * WIDTH + ix0) << 8;
    a11 = (iy1 * WIDTH + ix1) << 8;
  }

  // ---- P3/P4: bilinear build + GEMM1, two channel halves; + residual, A2 ----
  int n1 = wave & 3;
  int mh = wave >> 2;
  f32x4 acc0 = {0.f, 0.f, 0.f, 0.f};
  f32x4 acc1 = {0.f, 0.f, 0.f, 0.f};
  for (int h = 0; h < 2; ++h) {
    int co = (h << 7) + (ch8 << 4);
#pragma unroll 2
    for (int g = 0; g < 8; ++g) {
      int src = 8 * g + q8;
      float j0 = __shfl(w00, src), j1 = __shfl(w01, src);
      float j2 = __shfl(w10, src), j3 = __shfl(w11, src);
      int b0 = __shfl(a00, src), b1 = __shfl(a01, src);
      int b2 = __shfl(a10, src), b3 = __shfl(a11, src);
      float4 v0 = *(const float4*)(xbt + b0 + co);
      float4 v1 = *(const float4*)(xbt + b1 + co);
      float4 v2 = *(const float4*)(xbt + b2 + co);
      float4 v3 = *(const float4*)(xbt + b3 + co);
      float sx = j0 * v0.x + j1 * v1.x + j2 * v2.x + j3 * v3.x;
      float sy = j0 * v0.y + j1 * v1.y + j2 * v2.y + j3 * v3.y;
      float sz = j0 * v0.z + j1 * v1.z + j2 * v2.z + j3 * v3.z;
      float sw = j0 * v0.w + j1 * v1.w + j2 * v2.w + j3 * v3.w;
      unsigned int u0, u1;
      asm("v_cvt_pk_bf16_f32 %0, %1, %2" : "=v"(u0) : "v"(sx), "v"(sy));
      asm("v_cvt_pk_bf16_f32 %0, %1, %2" : "=v"(u1) : "v"(sz), "v"(sw));
      *(uint2*)((char*)A + kcbyte + src * 16) = make_uint2(u0, u1);
    }
    __syncthreads();
    if (wave < 8) {
      int r0r = mh * 32 + (lane & 15);
      const bf16x8* wp = (const bf16x8*)wBf;
      __builtin_amdgcn_s_setprio(1);
#pragma unroll
      for (int tap = 0; tap < 9; ++tap) {
        bf16x8 bk = wp[((2 * tap + h) * 4 + n1) * 64 + lane];
        int kc = tap * 4 + kq;
        bf16x8 a0 = *(const bf16x8*)((const char*)A + (kc * 65 + r0r) * 16);
        bf16x8 a1 = *(const bf16x8*)((const char*)A + (kc * 65 + r0r + 16) * 16);
        acc0 = __builtin_amdgcn_mfma_f32_16x16x32_bf16(a0, bk, acc0, 0, 0, 0);
        acc1 = __builtin_amdgcn_mfma_f32_16x16x32_bf16(a1, bk, acc1, 0, 0, 0);
      }
      __builtin_amdgcn_s_setprio(0);
    }
    __syncthreads();
  }
  // residual + A2 write (A fully consumed; barrier above)
  if (wave < 8) {
    int c = n1 * 16 + (lane & 15);
    int pb = px0 + mh * 32 + ((lane >> 4) << 2);
#pragma unroll
    for (int r = 0; r < 4; r++) {
      acc0[r] += xtf[(size_t)(pb + r) * 64 + c];
      acc1[r] += xtf[(size_t)(pb + 16 + r) * 64 + c];
    }
    char* base = (char*)A + (c >> 3) * 1040 + (c & 7) * 2;
    int pxr = mh * 32 + ((lane >> 4) << 2);
#pragma unroll
    for (int r = 0; r < 4; r++) {
      *(unsigned short*)(base + (size_t)(pxr + r) * 16) = f2bf(acc0[r]);
      *(unsigned short*)(base + (size_t)(pxr + 16 + r) * 16) = f2bf(acc1[r]);
    }
  }
  __syncthreads();
  if (wave >= 8) return;

  // ---- P6: GEMM2 (M=64, N=256, K=64) + GN2 partials + bf16 t3 ----
  f32x4 cA[4], cB[4];
#pragma unroll
  for (int ni = 0; ni < 4; ni++) {
    cA[ni] = (f32x4){0.f, 0.f, 0.f, 0.f};
    cB[ni] = (f32x4){0.f, 0.f, 0.f, 0.f};
  }
  {
    int mt0 = (wave >> 2) * 2;
    const bf16x8* wp2 = (const bf16x8*)w3Bf;
    __builtin_amdgcn_s_setprio(1);
#pragma unroll
    for (int kt = 0; kt < 2; kt++) {
      int kc = kt * 4 + kq;
      bf16x8 aA = *(const bf16x8*)((const char*)A + (size_t)(kc * 65 + mt0 * 16 + (lane & 15)) * 16);
      bf16x8 aB = *(const bf16x8*)((const char*)A + (size_t)(kc * 65 + (mt0 + 1) * 16 + (lane & 15)) * 16);
#pragma unroll
      for (int ni = 0; ni < 4; ni++) {
        int ng = n1 * 4 + ni;
        bf16x8 bk = wp2[(kt * 16 + ng) * 64 + lane];
        cA[ni] = __builtin_amdgcn_mfma_f32_16x16x32_bf16(aA, bk, cA[ni], 0, 0, 0);
        cB[ni] = __builtin_amdgcn_mfma_f32_16x16x32_bf16(aB, bk, cB[ni], 0, 0, 0);
      }
    }
    __builtin_amdgcn_s_setprio(0);
  }
#pragma unroll
  for (int ni = 0; ni < 4; ni++) {
    float s = 0.f, qq = 0.f;
#pragma unroll
    for (int r = 0; r < 4; r++) {
      float v0 = cA[ni][r], v1 = cB[ni][r];
      s += v0 + v1; qq += v0 * v0 + v1 * v1;
    }
    s += __shfl_down(s, 32); qq += __shfl_down(qq, 32);
    s += __shfl_down(s, 16); qq += __shfl_down(qq, 16);
    s += __shfl_down(s, 4);  qq += __shfl_down(qq, 4);
    s += __shfl_down(s, 2);  qq += __shfl_down(qq, 2);
    s += __shfl_down(s, 1);  qq += __shfl_down(qq, 1);
    if (lane == 0 || lane == 8) {
      int g = (n1 * 4 + ni) * 2 + (lane >> 3);
      int slot = ((bb * 32 + g) * 256 + tileid) * 2 + (wave >> 2);
      ps2[slot * 2] = s;
      ps2[slot * 2 + 1] = qq;
    }
  }
  unsigned short* tb = t3 + (size_t)bb * 256 * HW + px0;
  int mtq = (wave >> 2) * 32 + ((lane >> 4) << 2);
#pragma unroll
  for (int ni = 0; ni < 4; ni++) {
    int o = (n1 * 4 + ni) * 16 + (lane & 15);
    unsigned short* p0 = tb + (size_t)o * HW + mtq;
    unsigned int u0, u1, u2, u3;
    asm("v_cvt_pk_bf16_f32 %0, %1, %2" : "=v"(u0) : "v"(cA[ni][0]), "v"(cA[ni][1]));
    asm("v_cvt_pk_bf16_f32 %0, %1, %2" : "=v"(u1) : "v"(cA[ni][2]), "v"(cA[ni][3]));
    asm("v_cvt_pk_bf16_f32 %0, %1, %2" : "=v"(u2) : "v"(cB[ni][0]), "v"(cB[ni][1]));
    asm("v_cvt_pk_bf16_f32 %0, %1, %2" : "=v"(u3) : "v"(cB[ni][2]), "v"(cB[ni][3]));
    *(uint2*)p0 = make_uint2(u0, u1);
    *(uint2*)(p0 + 16) = make_uint2(u2, u3);
  }
}

// ---- K8: out = relu(gn2(t3_bf16)) + x ----
__global__ __launch_bounds__(256) void k_final(const unsigned short* __restrict__ t3, const float* __restrict__ x,
                                               const float* __restrict__ mrs, const float* __restrict__ g3,
                                               const float* __restrict__ b3, float* __restrict__ out) {
  int i4 = blockIdx.x * 256 + threadIdx.x;
  int b = i4 >> 20;
  int c = (i4 >> 12) & 255;
  int g = c >> 3;
  float mu = mrs[b * 32 + g], rs = mrs[128 + b * 32 + g];
  float ga = g3[c] * rs, be = b3[c] - mu * ga;
  uint2 tv = ((const uint2*)t3)[i4];
  float t0 = __uint_as_float(tv.x << 16);
  float t1 = __uint_as_float(tv.x & 0xffff0000u);
  float t2 = __uint_as_float(tv.y << 16);
  float t3v = __uint_as_float(tv.y & 0xffff0000u);
  float4 xv = ((const float4*)x)[i4];
  float4 r;
  r.x = fmaxf(t0 * ga + be, 0.f) + xv.x;
  r.y = fmaxf(t1 * ga + be, 0.f) + xv.y;
  r.z = fmaxf(t2 * ga + be, 0.f) + xv.z;
  r.w = fmaxf(t3v * ga + be, 0.f) + xv.w;
  ((float4*)out)[i4] = r;
}

extern "C" void kernel_launch(void* const* d_in, const int* in_sizes, int n_in,
                              void* d_out, int out_size, void* d_ws, size_t ws_size,
                              hipStream_t stream) {
  const float* x    = (const float*)d_in[0];
  const float* w1   = (const float*)d_in[1];
  const float* g1   = (const float*)d_in[2];
  const float* b1   = (const float*)d_in[3];
  const float* woff = (const float*)d_in[4];
  const float* wdef = (const float*)d_in[5];
  const float* w3   = (const float*)d_in[6];
  const float* g3   = (const float*)d_in[7];
  const float* b3   = (const float*)d_in[8];
  float* ws = (float*)d_ws;

  float* xdT  = ws;                       // 4,194,304 (NHWC)
  unsigned short* t3 = (unsigned short*)(xdT + 4194304);  // 16,777,216 ush = 8,388,608 fl
  float* base = xdT + 4194304 + 8388608;
  float* mrs1 = base;                     // 256
  float* mrs2 = mrs1 + 256;               // 256
  unsigned short* wA1f  = (unsigned short*)(mrs2 + 256);                        // 8,192 fl
  unsigned short* wBf   = (unsigned short*)(mrs2 + 256 + 8192);                 // 18,432 fl
  unsigned short* wofBf = (unsigned short*)(mrs2 + 256 + 8192 + 18432);         // 9,216 fl
  unsigned short* w3Bf  = (unsigned short*)(mrs2 + 256 + 8192 + 18432 + 9216);  // 16,384 fl
  float* ps   = mrs2 + 256 + 8192 + 18432 + 9216 + 16384;  // 65,536
  float* ps2  = ps + 65536;               // 131,072
  float* out  = (float*)d_out;

  hipLaunchKernelGGL(k_prep, dim3(144), dim3(256), 0, stream, w1, w3, wdef, woff, wA1f, wBf, wofBf, w3Bf);
  hipLaunchKernelGGL(k_conv1m, dim3(1024), dim3(256), 0, stream, x, wA1f, xdT, ps);
  hipLaunchKernelGGL(k_gnfin_p, dim3(128), dim3(256), 0, stream, ps, mrs1, 256, (float)(2 * HW));
  hipLaunchKernelGGL(k_gnapply, dim3(4096), dim3(256), 0, stream, xdT, mrs1, g1, b1);
  hipLaunchKernelGGL(k_mega, dim3(1024), dim3(576), 0, stream, xdT, wofBf, wBf, w3Bf, t3, ps2);
  hipLaunchKernelGGL(k_gnfin_p, dim3(128), dim3(256), 0, stream, ps2, mrs2, 512, 131072.f);
  hipLaunchKernelGGL(k_final, dim3(16384), dim3(256), 0, stream, t3, x, mrs2, g3, b3, out);
}

// Round 14
// 110.860 us; speedup vs baseline: 1.5669x; 1.1568x over previous
//
#include <hip/hip_runtime.h>

// deformMP: B=4, Cc=256, ci=64, H=W=128, GN groups=32, eps=1e-5
// ws (floats, no aliases, ~43 MB):
//   xdTbf[2.10M fl-equiv (ushort, NHWC bf16)] t3bf[8.39M fl-equiv] mrs1[256] mrs2[256]
//   wA1f[8.2K] wBf[18.4K] wofBf[9.2K] w3Bf[16.4K] ps[65.5K] ps2[131K]
// offs lives entirely in LDS inside k_mega. K-split by channel half (kt = 2*tap+h).

#define HW 16384
#define WIDTH 128

typedef __attribute__((ext_vector_type(8))) short bf16x8;
typedef __attribute__((ext_vector_type(4))) float f32x4;

__device__ __forceinline__ unsigned short f2bf(float f) {
  unsigned int u = __float_as_uint(f);
  u = (u + 0x7fffu + ((u >> 16) & 1u)) >> 16;  // RNE
  return (unsigned short)u;
}
__device__ __forceinline__ float bflo(unsigned int u) { return __uint_as_float(u << 16); }
__device__ __forceinline__ float bfhi(unsigned int u) { return __uint_as_float(u & 0xffff0000u); }

// ---- K0: weight repack (unchanged) ----
__global__ __launch_bounds__(256) void k_prep(const float* __restrict__ w1, const float* __restrict__ w3,
                                              const float* __restrict__ wdef, const float* __restrict__ woff,
                                              unsigned short* __restrict__ wA1f,
                                              unsigned short* __restrict__ wBf,
                                              unsigned short* __restrict__ wofBf,
                                              unsigned short* __restrict__ w3Bf) {
  int i = blockIdx.x * 256 + threadIdx.x;
  if (i < 16384) {
    int j = i & 7;
    int lane = (i >> 3) & 63;
    int m = (i >> 9) & 3;
    int kt = i >> 11;
    int o = (m << 4) + (lane & 15);
    int c = kt * 32 + ((lane >> 4) << 3) + j;
    wA1f[i] = f2bf(w1[(size_t)o * 256 + c]);
  }
  if (i < 36864) {
    int j = i & 7;
    int lane = (i >> 3) & 63;
    int n = (i >> 9) & 3;
    int kt = i >> 11;
    int kk = kt * 32 + ((lane >> 4) << 3) + j;
    int tap = kk >> 6, c = kk & 63;
    int o = (n << 4) + (lane & 15);
    wBf[i] = f2bf(wdef[(size_t)o * 576 + c * 9 + tap]);
  }
  if (i < 18432) {
    int j = i & 7;
    int lane = (i >> 3) & 63;
    int n = (i >> 9) & 1;
    int kt = i >> 10;
    int kk = kt * 32 + ((lane >> 4) << 3) + j;
    int tap = kk >> 6, c = kk & 63;
    int o = (n << 4) + (lane & 15);
    wofBf[i] = (o < 18) ? f2bf(woff[((size_t)(o * 64 + c)) * 9 + tap]) : (unsigned short)0;
  }
  if (i < 32768) {
    int j = i & 7;
    int lane = (i >> 3) & 63;
    int n = (i >> 9) & 15;
    int kt = i >> 13;
    int c = kt * 32 + ((lane >> 4) << 3) + j;
    int o = (n << 4) + (lane & 15);
    w3Bf[i] = f2bf(w3[(size_t)o * 64 + c]);
  }
}

// ---- K1: conv1x1 256->64 via bf16 MFMA, bf16 NHWC output + GN1 partials ----
__global__ __launch_bounds__(256) void k_conv1m(const float* __restrict__ x,
                                                const unsigned short* __restrict__ wA1f,
                                                unsigned short* __restrict__ xdT, float* __restrict__ ps) {
  __shared__ unsigned short xs[64][72];
  __shared__ float lds_s[4][32], lds_ss[4][32];
  int tid = threadIdx.x;
  int wave = tid >> 6, lane = tid & 63;
  int b = blockIdx.x >> 8;
  int chunk = blockIdx.x & 255;
  int px0 = chunk << 6;
  int pxl = lane & 15, q = lane >> 4;
  const float* xb = x + (size_t)b * 256 * HW + px0;
  const bf16x8* wAp = (const bf16x8*)wA1f;
  f32x4 acc[4];
#pragma unroll
  for (int m = 0; m < 4; m++) acc[m] = (f32x4){0.f, 0.f, 0.f, 0.f};

  for (int cb = 0; cb < 4; cb++) {
    __syncthreads();
#pragma unroll
    for (int r = 0; r < 4; r++) {
      int idx = r * 256 + tid;
      int c = idx >> 4;
      int qd = idx & 15;
      float4 v = *(const float4*)(xb + (size_t)(cb * 64 + c) * HW + qd * 4);
      xs[qd * 4 + 0][c] = f2bf(v.x);
      xs[qd * 4 + 1][c] = f2bf(v.y);
      xs[qd * 4 + 2][c] = f2bf(v.z);
      xs[qd * 4 + 3][c] = f2bf(v.w);
    }
    __syncthreads();
#pragma unroll
    for (int kt = 0; kt < 2; kt++) {
      bf16x8 bfrag = *(const bf16x8*)&xs[wave * 16 + pxl][kt * 32 + q * 8];
      int ktG = cb * 2 + kt;
#pragma unroll
      for (int m = 0; m < 4; m++) {
        bf16x8 af = wAp[(ktG * 4 + m) * 64 + lane];
        acc[m] = __builtin_amdgcn_mfma_f32_16x16x32_bf16(af, bfrag, acc[m], 0, 0, 0);
      }
    }
  }
  // bf16 NHWC stores: xdT[px][o], o = m*16 + q*4 + r
  unsigned short* xo = xdT + ((size_t)b * HW + px0 + wave * 16 + pxl) * 64 + (q << 2);
#pragma unroll
  for (int m = 0; m < 4; m++) {
    unsigned int u0, u1;
    asm("v_cvt_pk_bf16_f32 %0, %1, %2" : "=v"(u0) : "v"(acc[m][0]), "v"(acc[m][1]));
    asm("v_cvt_pk_bf16_f32 %0, %1, %2" : "=v"(u1) : "v"(acc[m][2]), "v"(acc[m][3]));
    *(uint2*)(xo + m * 16) = make_uint2(u0, u1);
  }
  float s[8], sq[8];
#pragma unroll
  for (int m = 0; m < 4; m++)
#pragma unroll
    for (int h = 0; h < 2; h++) {
      float a = acc[m][2 * h] + acc[m][2 * h + 1];
      float qq = acc[m][2 * h] * acc[m][2 * h] + acc[m][2 * h + 1] * acc[m][2 * h + 1];
      s[m * 2 + h] = a; sq[m * 2 + h] = qq;
    }
#pragma unroll
  for (int i = 0; i < 8; i++) {
#pragma unroll
    for (int off = 8; off; off >>= 1) {
      s[i] += __shfl_down(s[i], off, 16);
      sq[i] += __shfl_down(sq[i], off, 16);
    }
  }
  if (pxl == 0) {
#pragma unroll
    for (int i = 0; i < 8; i++) {
      int m = i >> 1, h = i & 1;
      int g = m * 8 + q * 2 + h;
      lds_s[wave][g] = s[i];
      lds_ss[wave][g] = sq[i];
    }
  }
  __syncthreads();
  if (tid < 32) {
    float S = lds_s[0][tid] + lds_s[1][tid] + lds_s[2][tid] + lds_s[3][tid];
    float SS = lds_ss[0][tid] + lds_ss[1][tid] + lds_ss[2][tid] + lds_ss[3][tid];
    int bg = b * 32 + tid;
    ps[(bg * 256 + chunk) * 2] = S;
    ps[(bg * 256 + chunk) * 2 + 1] = SS;
  }
}

// ---- K2: finalize GN stats, block-parallel ----
__global__ __launch_bounds__(256) void k_gnfin_p(const float* __restrict__ ps, float* __restrict__ mrs,
                                                 int S, float n) {
  int bg = blockIdx.x;
  float s = 0.f, ss = 0.f;
  for (int i = threadIdx.x; i < S; i += 256) { s += ps[(bg * S + i) * 2]; ss += ps[(bg * S + i) * 2 + 1]; }
#pragma unroll
  for (int off = 32; off; off >>= 1) { s += __shfl_down(s, off); ss += __shfl_down(ss, off); }
  __shared__ float ls[4], lss[4];
  int wv = threadIdx.x >> 6;
  if ((threadIdx.x & 63) == 0) { ls[wv] = s; lss[wv] = ss; }
  __syncthreads();
  if (threadIdx.x == 0) {
    float Sa = ls[0] + ls[1] + ls[2] + ls[3];
    float SSa = lss[0] + lss[1] + lss[2] + lss[3];
    float mu = Sa / n;
    float var = SSa / n - mu * mu;
    mrs[bg] = mu;
    mrs[128 + bg] = rsqrtf(var + 1e-5f);
  }
}

// ---- K3: GN1 + ReLU in place on bf16 xdT (ushort8 per lane) ----
__global__ __launch_bounds__(256) void k_gnapply_bf(unsigned short* __restrict__ xdT,
                                                    const float* __restrict__ mrs,
                                                    const float* __restrict__ g1, const float* __restrict__ b1) {
  int i = blockIdx.x * 256 + threadIdx.x;  // 524,288 uint4 chunks (8 ch each)
  int b = i >> 17;
  int ck = i & 7;
  int c0 = ck << 3;
  uint4 v = ((const uint4*)xdT)[i];
  float ga[8], be[8];
#pragma unroll
  for (int j = 0; j < 8; j += 2) {
    int g = (c0 + j) >> 1;
    float mu = mrs[b * 32 + g], rs = mrs[128 + b * 32 + g];
    ga[j] = g1[c0 + j] * rs;     be[j] = b1[c0 + j] - mu * ga[j];
    ga[j + 1] = g1[c0 + j + 1] * rs; be[j + 1] = b1[c0 + j + 1] - mu * ga[j + 1];
  }
  float r[8];
  r[0] = fmaxf(bflo(v.x) * ga[0] + be[0], 0.f);
  r[1] = fmaxf(bfhi(v.x) * ga[1] + be[1], 0.f);
  r[2] = fmaxf(bflo(v.y) * ga[2] + be[2], 0.f);
  r[3] = fmaxf(bfhi(v.y) * ga[3] + be[3], 0.f);
  r[4] = fmaxf(bflo(v.z) * ga[4] + be[4], 0.f);
  r[5] = fmaxf(bfhi(v.z) * ga[5] + be[5], 0.f);
  r[6] = fmaxf(bflo(v.w) * ga[6] + be[6], 0.f);
  r[7] = fmaxf(bfhi(v.w) * ga[7] + be[7], 0.f);
  uint4 o;
  asm("v_cvt_pk_bf16_f32 %0, %1, %2" : "=v"(o.x) : "v"(r[0]), "v"(r[1]));
  asm("v_cvt_pk_bf16_f32 %0, %1, %2" : "=v"(o.y) : "v"(r[2]), "v"(r[3]));
  asm("v_cvt_pk_bf16_f32 %0, %1, %2" : "=v"(o.z) : "v"(r[4]), "v"(r[5]));
  asm("v_cvt_pk_bf16_f32 %0, %1, %2" : "=v"(o.w) : "v"(r[6]), "v"(r[7]));
  ((uint4*)xdT)[i] = o;
}

// ---- K5: MEGA v3 — bf16 gathers, wide build tasks (8ch/16B per lane-task).
// Build lanes: (q16 = lane>>2 pair-sub, ch4 = lane&3 8-ch chunk). 4 iters/half.
__global__ __launch_bounds__(576, 7) void k_mega(const unsigned short* __restrict__ xdT,
                                                 const unsigned short* __restrict__ wofBf,
                                                 const unsigned short* __restrict__ wBf,
                                                 const unsigned short* __restrict__ w3Bf,
                                                 unsigned short* __restrict__ t3,
                                                 float* __restrict__ ps2) {
  __shared__ unsigned short A[36 * 65 * 8];  // 37,440 B
  __shared__ float offsL[64 * 18];           // 4,608 B
  int tid = threadIdx.x;
  int bb = blockIdx.x >> 8;
  int tileid = blockIdx.x & 255;
  int px0 = tileid << 6;
  const unsigned short* xtf = xdT + (size_t)bb * 64 * HW;  // bf16 NHWC
  const char* xbt = (const char*)xtf;
  int wave = tid >> 6;  // 0..8 = tap in build phases
  int lane = tid & 63;
  int q16 = lane >> 2;  // pair-sub 0..15
  int ch4 = lane & 3;   // 8-ch chunk within 32-ch half
  int kcbyte = (wave * 4 + ch4) * 1040;
  int kq = lane >> 4;

  // ---- P0/P1: fixed-tap build + off-GEMM, two channel halves ----
  f32x4 aoff = {0.f, 0.f, 0.f, 0.f};
  {
    int ky = wave / 3 - 1, kx = wave % 3 - 1;
    int n2 = wave & 1;
    int mh1 = wave >> 1;
    int r1 = mh1 * 16 + (lane & 15);
    for (int h = 0; h < 2; ++h) {
      int co = (h << 6) + (ch4 << 4);  // byte: h*64 + ch4*16
#pragma unroll
      for (int g = 0; g < 4; ++g) {
        int src = (g << 4) + q16;
        int px = px0 + src;
        int sy = (px >> 7) + ky;
        int sx = (px & 127) + kx;
        bool valid = ((unsigned)sy < 128u) && ((unsigned)sx < 128u);
        uint4 v = make_uint4(0u, 0u, 0u, 0u);
        if (valid) v = *(const uint4*)(xbt + (((sy << 7) + sx) << 7) + co);
        *(uint4*)((char*)A + kcbyte + src * 16) = v;
      }
      __syncthreads();
      if (wave < 8) {
        const bf16x8* wp = (const bf16x8*)wofBf;
        __builtin_amdgcn_s_setprio(1);
#pragma unroll
        for (int tap = 0; tap < 9; ++tap) {
          bf16x8 bk = wp[((2 * tap + h) * 2 + n2) * 64 + lane];
          bf16x8 a0 = *(const bf16x8*)((const char*)A + ((tap * 4 + kq) * 65 + r1) * 16);
          aoff = __builtin_amdgcn_mfma_f32_16x16x32_bf16(a0, bk, aoff, 0, 0, 0);
        }
        __builtin_amdgcn_s_setprio(0);
      }
      __syncthreads();
    }
    if (wave < 8) {
      int o = n2 * 16 + (lane & 15);
      if (o < 18) {
        int prow = mh1 * 16 + ((lane >> 4) << 2);
#pragma unroll
        for (int r = 0; r < 4; r++) offsL[(prow + r) * 18 + o] = aoff[r];
      }
    }
  }
  __syncthreads();

  // ---- P2: geometry from offsL (pxl = lane, tap = wave); byte addrs for bf16 (px<<7) ----
  float w00, w01, w10, w11;
  int a00, a01, a10, a11;
  {
    int px = px0 + lane;
    int y = px >> 7, xc = px & 127;
    float dy = offsL[lane * 18 + 2 * wave];
    float dx = offsL[lane * 18 + 2 * wave + 1];
    float py = (float)(y + wave / 3 - 1) + dy;
    float pxx = (float)(xc + wave % 3 - 1) + dx;
    float y0f = floorf(py), x0f = floorf(pxx);
    float ay = py - y0f, ax = pxx - x0f;
    int y0 = (int)y0f, x0 = (int)x0f;
    int y1i = y0 + 1, x1i = x0 + 1;
    float by0 = 1.f - ay, bx0 = 1.f - ax;
    bool vy0 = (unsigned)y0 < 128u, vy1 = (unsigned)y1i < 128u;
    bool vx0 = (unsigned)x0 < 128u, vx1 = (unsigned)x1i < 128u;
    w00 = (vy0 && vx0) ? by0 * bx0 : 0.f;
    w01 = (vy0 && vx1) ? by0 * ax : 0.f;
    w10 = (vy1 && vx0) ? ay * bx0 : 0.f;
    w11 = (vy1 && vx1) ? ay * ax : 0.f;
    int iy0 = min(max(y0, 0), 127), iy1 = min(max(y1i, 0), 127);
    int ix0 = min(max(x0, 0), 127), ix1 = min(max(x1i, 0), 127);
    a00 = (iy0 * WIDTH + ix0) << 7;
    a01 = (iy0 * WIDTH + ix1) << 7;
    a10 = (iy1 * WIDTH + ix0) << 7;
    a11 = (iy1 * WIDTH + ix1) << 7;
  }

  // ---- P3/P4: bilinear build + GEMM1, two channel halves; + residual, A2 ----
  int n1 = wave & 3;
  int mh = wave >> 2;
  f32x4 acc0 = {0.f, 0.f, 0.f, 0.f};
  f32x4 acc1 = {0.f, 0.f, 0.f, 0.f};
  for (int h = 0; h < 2; ++h) {
    int co = (h << 6) + (ch4 << 4);
#pragma unroll
    for (int g = 0; g < 4; ++g) {
      int src = (g << 4) + q16;
      float j0 = __shfl(w00, src), j1 = __shfl(w01, src);
      float j2 = __shfl(w10, src), j3 = __shfl(w11, src);
      int b0 = __shfl(a00, src), b1 = __shfl(a01, src);
      int b2 = __shfl(a10, src), b3 = __shfl(a11, src);
      uint4 v0 = *(const uint4*)(xbt + b0 + co);
      uint4 v1 = *(const uint4*)(xbt + b1 + co);
      uint4 v2 = *(const uint4*)(xbt + b2 + co);
      uint4 v3 = *(const uint4*)(xbt + b3 + co);
      float r[8];
      r[0] = j0 * bflo(v0.x) + j1 * bflo(v1.x) + j2 * bflo(v2.x) + j3 * bflo(v3.x);
      r[1] = j0 * bfhi(v0.x) + j1 * bfhi(v1.x) + j2 * bfhi(v2.x) + j3 * bfhi(v3.x);
      r[2] = j0 * bflo(v0.y) + j1 * bflo(v1.y) + j2 * bflo(v2.y) + j3 * bflo(v3.y);
      r[3] = j0 * bfhi(v0.y) + j1 * bfhi(v1.y) + j2 * bfhi(v2.y) + j3 * bfhi(v3.y);
      r[4] = j0 * bflo(v0.z) + j1 * bflo(v1.z) + j2 * bflo(v2.z) + j3 * bflo(v3.z);
      r[5] = j0 * bfhi(v0.z) + j1 * bfhi(v1.z) + j2 * bfhi(v2.z) + j3 * bfhi(v3.z);
      r[6] = j0 * bflo(v0.w) + j1 * bflo(v1.w) + j2 * bflo(v2.w) + j3 * bflo(v3.w);
      r[7] = j0 * bfhi(v0.w) + j1 * bfhi(v1.w) + j2 * bfhi(v2.w) + j3 * bfhi(v3.w);
      uint4 ov;
      asm("v_cvt_pk_bf16_f32 %0, %1, %2" : "=v"(ov.x) : "v"(r[0]), "v"(r[1]));
      asm("v_cvt_pk_bf16_f32 %0, %1, %2" : "=v"(ov.y) : "v"(r[2]), "v"(r[3]));
      asm("v_cvt_pk_bf16_f32 %0, %1, %2" : "=v"(ov.z) : "v"(r[4]), "v"(r[5]));
      asm("v_cvt_pk_bf16_f32 %0, %1, %2" : "=v"(ov.w) : "v"(r[6]), "v"(r[7]));
      *(uint4*)((char*)A + kcbyte + src * 16) = ov;
    }
    __syncthreads();
    if (wave < 8) {
      int r0r = mh * 32 + (lane & 15);
      const bf16x8* wp = (const bf16x8*)wBf;
      __builtin_amdgcn_s_setprio(1);
#pragma unroll
      for (int tap = 0; tap < 9; ++tap) {
        bf16x8 bk = wp[((2 * tap + h) * 4 + n1) * 64 + lane];
        int kc = tap * 4 + kq;
        bf16x8 a0 = *(const bf16x8*)((const char*)A + (kc * 65 + r0r) * 16);
        bf16x8 a1 = *(const bf16x8*)((const char*)A + (kc * 65 + r0r + 16) * 16);
        acc0 = __builtin_amdgcn_mfma_f32_16x16x32_bf16(a0, bk, acc0, 0, 0, 0);
        acc1 = __builtin_amdgcn_mfma_f32_16x16x32_bf16(a1, bk, acc1, 0, 0, 0);
      }
      __builtin_amdgcn_s_setprio(0);
    }
    __syncthreads();
  }
  // residual (bf16 unpack) + A2 write
  if (wave < 8) {
    int c = n1 * 16 + (lane & 15);
    int pb = px0 + mh * 32 + ((lane >> 4) << 2);
#pragma unroll
    for (int r = 0; r < 4; r++) {
      acc0[r] += __uint_as_float((unsigned int)xtf[(size_t)(pb + r) * 64 + c] << 16);
      acc1[r] += __uint_as_float((unsigned int)xtf[(size_t)(pb + 16 + r) * 64 + c] << 16);
    }
    char* base = (char*)A + (c >> 3) * 1040 + (c & 7) * 2;
    int pxr = mh * 32 + ((lane >> 4) << 2);
#pragma unroll
    for (int r = 0; r < 4; r++) {
      *(unsigned short*)(base + (size_t)(pxr + r) * 16) = f2bf(acc0[r]);
      *(unsigned short*)(base + (size_t)(pxr + 16 + r) * 16) = f2bf(acc1[r]);
    }
  }
  __syncthreads();
  if (wave >= 8) return;

  // ---- P6: GEMM2 (M=64, N=256, K=64) + GN2 partials + bf16 t3 ----
  f32x4 cA[4], cB[4];
#pragma unroll
  for (int ni = 0; ni < 4; ni++) {
    cA[ni] = (f32x4){0.f, 0.f, 0.f, 0.f};
    cB[ni] = (f32x4){0.f, 0.f, 0.f, 0.f};
  }
  {
    int mt0 = (wave >> 2) * 2;
    const bf16x8* wp2 = (const bf16x8*)w3Bf;
    __builtin_amdgcn_s_setprio(1);
#pragma unroll
    for (int kt = 0; kt < 2; kt++) {
      int kc = kt * 4 + kq;
      bf16x8 aA = *(const bf16x8*)((const char*)A + (size_t)(kc * 65 + mt0 * 16 + (lane & 15)) * 16);
      bf16x8 aB = *(const bf16x8*)((const char*)A + (size_t)(kc * 65 + (mt0 + 1) * 16 + (lane & 15)) * 16);
#pragma unroll
      for (int ni = 0; ni < 4; ni++) {
        int ng = n1 * 4 + ni;
        bf16x8 bk = wp2[(kt * 16 + ng) * 64 + lane];
        cA[ni] = __builtin_amdgcn_mfma_f32_16x16x32_bf16(aA, bk, cA[ni], 0, 0, 0);
        cB[ni] = __builtin_amdgcn_mfma_f32_16x16x32_bf16(aB, bk, cB[ni], 0, 0, 0);
      }
    }
    __builtin_amdgcn_s_setprio(0);
  }
#pragma unroll
  for (int ni = 0; ni < 4; ni++) {
    float s = 0.f, qq = 0.f;
#pragma unroll
    for (int r = 0; r < 4; r++) {
      float v0 = cA[ni][r], v1 = cB[ni][r];
      s += v0 + v1; qq += v0 * v0 + v1 * v1;
    }
    s += __shfl_down(s, 32); qq += __shfl_down(qq, 32);
    s += __shfl_down(s, 16); qq += __shfl_down(qq, 16);
    s += __shfl_down(s, 4);  qq += __shfl_down(qq, 4);
    s += __shfl_down(s, 2);  qq += __shfl_down(qq, 2);
    s += __shfl_down(s, 1);  qq += __shfl_down(qq, 1);
    if (lane == 0 || lane == 8) {
      int g = (n1 * 4 + ni) * 2 + (lane >> 3);
      int slot = ((bb * 32 + g) * 256 + tileid) * 2 + (wave >> 2);
      ps2[slot * 2] = s;
      ps2[slot * 2 + 1] = qq;
    }
  }
  unsigned short* tb = t3 + (size_t)bb * 256 * HW + px0;
  int mtq = (wave >> 2) * 32 + ((lane >> 4) << 2);
#pragma unroll
  for (int ni = 0; ni < 4; ni++) {
    int o = (n1 * 4 + ni) * 16 + (lane & 15);
    unsigned short* p0 = tb + (size_t)o * HW + mtq;
    unsigned int u0, u1, u2, u3;
    asm("v_cvt_pk_bf16_f32 %0, %1, %2" : "=v"(u0) : "v"(cA[ni][0]), "v"(cA[ni][1]));
    asm("v_cvt_pk_bf16_f32 %0, %1, %2" : "=v"(u1) : "v"(cA[ni][2]), "v"(cA[ni][3]));
    asm("v_cvt_pk_bf16_f32 %0, %1, %2" : "=v"(u2) : "v"(cB[ni][0]), "v"(cB[ni][1]));
    asm("v_cvt_pk_bf16_f32 %0, %1, %2" : "=v"(u3) : "v"(cB[ni][2]), "v"(cB[ni][3]));
    *(uint2*)p0 = make_uint2(u0, u1);
    *(uint2*)(p0 + 16) = make_uint2(u2, u3);
  }
}

// ---- K8: out = relu(gn2(t3_bf16)) + x ----
__global__ __launch_bounds__(256) void k_final(const unsigned short* __restrict__ t3, const float* __restrict__ x,
                                               const float* __restrict__ mrs, const float* __restrict__ g3,
                                               const float* __restrict__ b3, float* __restrict__ out) {
  int i4 = blockIdx.x * 256 + threadIdx.x;
  int b = i4 >> 20;
  int c = (i4 >> 12) & 255;
  int g = c >> 3;
  float mu = mrs[b * 32 + g], rs = mrs[128 + b * 32 + g];
  float ga = g3[c] * rs, be = b3[c] - mu * ga;
  uint2 tv = ((const uint2*)t3)[i4];
  float t0 = bflo(tv.x);
  float t1 = bfhi(tv.x);
  float t2 = bflo(tv.y);
  float t3v = bfhi(tv.y);
  float4 xv = ((const float4*)x)[i4];
  float4 r;
  r.x = fmaxf(t0 * ga + be, 0.f) + xv.x;
  r.y = fmaxf(t1 * ga + be, 0.f) + xv.y;
  r.z = fmaxf(t2 * ga + be, 0.f) + xv.z;
  r.w = fmaxf(t3v * ga + be, 0.f) + xv.w;
  ((float4*)out)[i4] = r;
}

extern "C" void kernel_launch(void* const* d_in, const int* in_sizes, int n_in,
                              void* d_out, int out_size, void* d_ws, size_t ws_size,
                              hipStream_t stream) {
  const float* x    = (const float*)d_in[0];
  const float* w1   = (const float*)d_in[1];
  const float* g1   = (const float*)d_in[2];
  const float* b1   = (const float*)d_in[3];
  const float* woff = (const float*)d_in[4];
  const float* wdef = (const float*)d_in[5];
  const float* w3   = (const float*)d_in[6];
  const float* g3   = (const float*)d_in[7];
  const float* b3   = (const float*)d_in[8];
  float* ws = (float*)d_ws;

  unsigned short* xdT = (unsigned short*)ws;               // 4,194,304 ush = 2,097,152 fl
  unsigned short* t3  = (unsigned short*)(ws + 2097152);   // 16,777,216 ush = 8,388,608 fl
  float* base = ws + 2097152 + 8388608;
  float* mrs1 = base;                     // 256
  float* mrs2 = mrs1 + 256;               // 256
  unsigned short* wA1f  = (unsigned short*)(mrs2 + 256);                        // 8,192 fl
  unsigned short* wBf   = (unsigned short*)(mrs2 + 256 + 8192);                 // 18,432 fl
  unsigned short* wofBf = (unsigned short*)(mrs2 + 256 + 8192 + 18432);         // 9,216 fl
  unsigned short* w3Bf  = (unsigned short*)(mrs2 + 256 + 8192 + 18432 + 9216);  // 16,384 fl
  float* ps   = mrs2 + 256 + 8192 + 18432 + 9216 + 16384;  // 65,536
  float* ps2  = ps + 65536;               // 131,072
  float* out  = (float*)d_out;

  hipLaunchKernelGGL(k_prep, dim3(144), dim3(256), 0, stream, w1, w3, wdef, woff, wA1f, wBf, wofBf, w3Bf);
  hipLaunchKernelGGL(k_conv1m, dim3(1024), dim3(256), 0, stream, x, wA1f, xdT, ps);
  hipLaunchKernelGGL(k_gnfin_p, dim3(128), dim3(256), 0, stream, ps, mrs1, 256, (float)(2 * HW));
  hipLaunchKernelGGL(k_gnapply_bf, dim3(2048), dim3(256), 0, stream, xdT, mrs1, g1, b1);
  hipLaunchKernelGGL(k_mega, dim3(1024), dim3(576), 0, stream, xdT, wofBf, wBf, w3Bf, t3, ps2);
  hipLaunchKernelGGL(k_gnfin_p, dim3(128), dim3(256), 0, stream, ps2, mrs2, 512, 131072.f);
  hipLaunchKernelGGL(k_final, dim3(16384), dim3(256), 0, stream, t3, x, mrs2, g3, b3, out);
}